// Round 7
// baseline (710.873 us; speedup 1.0000x reference)
//
#include <hip/hip_runtime.h>
#include <hip/hip_bf16.h>
#include <math.h>

#define S_LEN 4096
#define DMODEL 768
#define NHEAD 12
#define HDIM 64
#define DFF_ 3072
#define MROWS 8192  // B*S

typedef __bf16 bf16;
typedef __bf16 bf16x4 __attribute__((ext_vector_type(4)));
typedef __bf16 bf16x8 __attribute__((ext_vector_type(8)));
typedef float f32x4 __attribute__((ext_vector_type(4)));

union F4 { float4 v; float f[4]; };
union U2 { bf16 h[2]; unsigned u; };
union U8 { unsigned u[4]; bf16x8 v; };

__device__ __forceinline__ void gld_lds16(void* lds, const void* g) {
    __builtin_amdgcn_global_load_lds(
        (const __attribute__((address_space(1))) unsigned int*)g,
        (__attribute__((address_space(3))) unsigned int*)lds, 16, 0, 0);
}

// ---------------- LayerNorm ----------------
template<typename OUT>
__global__ __launch_bounds__(256) void ln_kernel(const float* __restrict__ x,
                                                 const float* __restrict__ g,
                                                 const float* __restrict__ bta,
                                                 OUT* __restrict__ out) {
    const int row = blockIdx.x;
    const int t = threadIdx.x;
    const float* xr = x + (size_t)row * DMODEL;
    float v0 = xr[t], v1 = xr[t + 256], v2 = xr[t + 512];
    float s = v0 + v1 + v2;
    float ss = v0 * v0 + v1 * v1 + v2 * v2;
    for (int o = 32; o > 0; o >>= 1) {
        s += __shfl_down(s, o, 64);
        ss += __shfl_down(ss, o, 64);
    }
    __shared__ float sm[4], sm2[4];
    const int w = t >> 6, lane = t & 63;
    if (lane == 0) { sm[w] = s; sm2[w] = ss; }
    __syncthreads();
    s = sm[0] + sm[1] + sm[2] + sm[3];
    ss = sm2[0] + sm2[1] + sm2[2] + sm2[3];
    const float mu = s * (1.0f / DMODEL);
    const float var = ss * (1.0f / DMODEL) - mu * mu;
    const float rs = rsqrtf(var + 1e-5f);
    OUT* orow = out + (size_t)row * DMODEL;
    orow[t]       = (OUT)((v0 - mu) * rs * g[t]       + bta[t]);
    orow[t + 256] = (OUT)((v1 - mu) * rs * g[t + 256] + bta[t + 256]);
    orow[t + 512] = (OUT)((v2 - mu) * rs * g[t + 512] + bta[t + 512]);
}

// ---------------- weight transpose+convert: fp32 [K][N] -> bf16 [N][K] ----------------
__global__ __launch_bounds__(256) void wtrans_kernel(const float* __restrict__ W,
                                                     bf16* __restrict__ Wt,
                                                     int K, int N) {
    __shared__ float tile[64][65];
    const int tid = threadIdx.x;
    const int n0 = blockIdx.x * 64, k0 = blockIdx.y * 64;
    const int lr = tid >> 4, lc = (tid & 15) << 2;
#pragma unroll
    for (int i = 0; i < 4; ++i) {
        const int r = lr + i * 16;
        F4 w; w.v = *(const float4*)&W[(size_t)(k0 + r) * N + n0 + lc];
#pragma unroll
        for (int j = 0; j < 4; ++j) tile[r][lc + j] = w.f[j];
    }
    __syncthreads();
#pragma unroll
    for (int i = 0; i < 4; ++i) {
        const int n = lr + i * 16;
        bf16x4 o;
#pragma unroll
        for (int j = 0; j < 4; ++j) o[j] = (bf16)tile[lc + j][n];
        *(bf16x4*)&Wt[(size_t)(n0 + n) * K + k0 + lc] = o;
    }
}

// ---------------- bf16 MFMA GEMM (m97 structure), MT x 128 tile ----------------
template<int MT, bool RELU, bool RES, bool OUT_BF16>
__global__ __launch_bounds__(256) void mgemm_kernel(
    const bf16* __restrict__ A,
    const bf16* __restrict__ Wt0, const float* __restrict__ bias0, void* __restrict__ C0,
    const bf16* __restrict__ Wt1, const float* __restrict__ bias1, void* __restrict__ C1,
    const bf16* __restrict__ Wt2, const float* __restrict__ bias2, void* __restrict__ C2,
    const float* __restrict__ R, int M, int N, int K,
    float sc0, float sc1, float sc2) {
    const bf16* Wt = Wt0; const float* bias = bias0; void* C = C0; float sc = sc0;
    if (blockIdx.z == 1) { Wt = Wt1; bias = bias1; C = C1; sc = sc1; }
    if (blockIdx.z == 2) { Wt = Wt2; bias = bias2; C = C2; sc = sc2; }

    constexpr int NI = (MT == 128) ? 4 : 2;
    __shared__ bf16 As[MT * 32];
    __shared__ bf16 Bs[128 * 32];

    const int tid = threadIdx.x;
    const int wave = tid >> 6, lane = tid & 63;
    const int row0 = blockIdx.y * MT, col0 = blockIdx.x * 128;
    const int wr = (MT == 128) ? (wave >> 1) * 64 : 0;
    const int wc = (MT == 128) ? (wave & 1) * 64 : wave * 32;
    const int mrow = lane & 15, kq = (lane >> 4) * 8;

    const int st_row = (lane >> 2);
    const int st_off = (lane & 3) * 16;

    f32x4 acc[4][NI] = {};

    const char* Ab = (const char*)(A + (size_t)row0 * K);
    const char* Bb = (const char*)(Wt + (size_t)col0 * K);
    const size_t strideA = (size_t)K * 2;

    for (int k0 = 0; k0 < K; k0 += 32) {
        if (MT == 128) {
#pragma unroll
            for (int issue = 0; issue < 2; ++issue) {
                const int r = wave * 32 + issue * 16 + st_row;
                gld_lds16((char*)As + (wave * 32 + issue * 16) * 64,
                          Ab + (size_t)r * strideA + k0 * 2 + st_off);
            }
        } else {
            const int r = wave * 16 + st_row;
            gld_lds16((char*)As + (wave * 16) * 64,
                      Ab + (size_t)r * strideA + k0 * 2 + st_off);
        }
#pragma unroll
        for (int issue = 0; issue < 2; ++issue) {
            const int r = wave * 32 + issue * 16 + st_row;
            gld_lds16((char*)Bs + (wave * 32 + issue * 16) * 64,
                      Bb + (size_t)r * strideA + k0 * 2 + st_off);
        }
        __syncthreads();
        bf16x8 af[4], bfr[NI];
#pragma unroll
        for (int mi = 0; mi < 4; ++mi)
            af[mi] = *(const bf16x8*)&As[(wr + mi * 16 + mrow) * 32 + kq];
#pragma unroll
        for (int ni = 0; ni < NI; ++ni)
            bfr[ni] = *(const bf16x8*)&Bs[(wc + ni * 16 + mrow) * 32 + kq];
#pragma unroll
        for (int mi = 0; mi < 4; ++mi)
#pragma unroll
            for (int ni = 0; ni < NI; ++ni)
                acc[mi][ni] = __builtin_amdgcn_mfma_f32_16x16x32_bf16(
                    af[mi], bfr[ni], acc[mi][ni], 0, 0, 0);
        __syncthreads();
    }

    const int quad = lane >> 4;
    float bv[NI];
#pragma unroll
    for (int ni = 0; ni < NI; ++ni) bv[ni] = bias[col0 + wc + ni * 16 + mrow];
#pragma unroll
    for (int mi = 0; mi < 4; ++mi) {
#pragma unroll
        for (int r = 0; r < 4; ++r) {
            const int row = row0 + wr + mi * 16 + quad * 4 + r;
#pragma unroll
            for (int ni = 0; ni < NI; ++ni) {
                const int col = col0 + wc + ni * 16 + mrow;
                float v = acc[mi][ni][r] + bv[ni];
                if (RES) v += R[(size_t)row * N + col];
                v *= sc;
                if (RELU) v = fmaxf(v, 0.0f);
                if (OUT_BF16) ((bf16*)C)[(size_t)row * N + col] = (bf16)v;
                else          ((float*)C)[(size_t)row * N + col] = v;
            }
        }
    }
}

// ---------------- Transposed-S MFMA flash attention, Br=128 ----------------
// Each wave serves 32 queries (2 groups of 16) with ONE set of K/V LDS frag
// reads -> per-query LDS traffic, staging, and barriers halve vs Br=64.
// S^T = K·Q^T; P^T re-layout via quad shfl; Q pre-scaled by 0.125*log2(e).
// grid (16,H,B) = 384 blocks, block does q-tiles {31-bx, bx} -> uniform 66
// iters. Double-buffered K/V. Group 0 skipped on its fully-masked tile.
__global__ __launch_bounds__(256, 2) void mattn_kernel(
    const bf16* __restrict__ Q, const bf16* __restrict__ K,
    const bf16* __restrict__ V, const int* __restrict__ amask,
    bf16* __restrict__ O) {
    const int bx = blockIdx.x, h = blockIdx.y, b = blockIdx.z;

    __shared__ __align__(16) char smem[2 * 17408 + 512 + 16];
    typedef bf16 Tile[64][68];                       // 8704 B per tile
    Tile* Ks = (Tile*)smem;                          // Ks[buf][key][d]
    Tile* Vt = (Tile*)(smem + 17408);                // Vt[buf][d][key]
    float* mk = (float*)(smem + 34816);              // [2][64]
    int* flagv = (int*)(smem + 34816 + 512);         // [2]
    bf16 (*Os)[68] = (bf16(*)[68])smem;              // [128][68] alias of Ks

    const int tid = threadIdx.x;
    const int wave = tid >> 6, lane = tid & 63;
    const int l = lane & 15, quad = lane >> 4;
    const int qh = quad >> 1;
    const int srcA = (quad & 1) * 32 + l;
    const int srcB = srcA + 16;
    const float NEG_INF = -__builtin_huge_valf();

    const int kr = tid >> 2, ks = (tid & 3) * 16;          // K tile staging
    const int vk0 = (tid & 31) * 2, vds = (tid >> 5) * 8;  // V transpose staging

    const bf16* Kbase = K + (size_t)b * S_LEN * DMODEL + h * HDIM;
    const bf16* Vbase = V + (size_t)b * S_LEN * DMODEL + h * HDIM;

#pragma unroll 1
    for (int pass = 0; pass < 2; ++pass) {
        const int qt = pass ? bx : (31 - bx);    // q-tile of 128 queries
        const int ktmax = 2 * qt + 1;

        // Q fragments (B-operand) for both q-groups, pre-scaled, in registers
        bf16x8 qf[2][2];
#pragma unroll
        for (int g = 0; g < 2; ++g) {
            const bf16* Qb = Q + (size_t)(b * S_LEN + qt * 128 + g * 64 + wave * 16 + l) * DMODEL + h * HDIM;
            qf[g][0] = *(const bf16x8*)(Qb + quad * 8);
            qf[g][1] = *(const bf16x8*)(Qb + 32 + quad * 8);
        }

        float m_run[2] = {NEG_INF, NEG_INF}, l_run[2] = {0.0f, 0.0f};
        f32x4 acc[2][4] = {};

        // ---- prefetch tile 0 into registers ----
        bf16x8 kp0, kp1, vp0, vp1;
        int mv = 1;
        {
            const bf16* kg = Kbase + (size_t)kr * DMODEL + ks;
            kp0 = *(const bf16x8*)kg;
            kp1 = *(const bf16x8*)(kg + 8);
            const bf16* vg = Vbase + (size_t)vk0 * DMODEL + vds;
            vp0 = *(const bf16x8*)vg;
            vp1 = *(const bf16x8*)(vg + DMODEL);
            if (wave == 0) mv = amask[b * S_LEN + lane];
        }
        __syncthreads();   // prior pass epilogue LDS reads complete
        {
            *(bf16x8*)&Ks[0][kr][ks]     = kp0;
            *(bf16x8*)&Ks[0][kr][ks + 8] = kp1;
#pragma unroll
            for (int i = 0; i < 8; ++i) {
                U2 w; w.h[0] = vp0[i]; w.h[1] = vp1[i];
                *(unsigned*)&Vt[0][vds + i][vk0] = w.u;
            }
            if (wave == 0) {
                mk[lane] = mv ? 0.0f : NEG_INF;
                unsigned long long bal = __ballot(mv != 0);
                if (lane == 0) flagv[0] = (bal == ~0ULL);
            }
        }
        __syncthreads();
        int buf = 0;

        for (int kt = 0; kt <= ktmax; ++kt) {
            const bool more = (kt < ktmax);
            if (more) {   // issue next tile's global loads
                const bf16* kg = Kbase + (size_t)((kt + 1) * 64 + kr) * DMODEL + ks;
                kp0 = *(const bf16x8*)kg;
                kp1 = *(const bf16x8*)(kg + 8);
                const bf16* vg = Vbase + (size_t)((kt + 1) * 64 + vk0) * DMODEL + vds;
                vp0 = *(const bf16x8*)vg;
                vp1 = *(const bf16x8*)(vg + DMODEL);
                if (wave == 0) mv = amask[b * S_LEN + (kt + 1) * 64 + lane];
            }

            const int allv = flagv[buf];
            const bool skip0 = (kt == 2 * qt + 1);   // group 0 fully masked

            // K frags read ONCE, used by both q-groups
            bf16x8 kf[4][2];
#pragma unroll
            for (int mi = 0; mi < 4; ++mi) {
                kf[mi][0] = *(const bf16x8*)&Ks[buf][mi * 16 + l][quad * 8];
                kf[mi][1] = *(const bf16x8*)&Ks[buf][mi * 16 + l][32 + quad * 8];
            }
            f32x4 sreg[2][4] = {};
#pragma unroll
            for (int g = 0; g < 2; ++g) {
                if (g == 0 && skip0) continue;
#pragma unroll
                for (int mi = 0; mi < 4; ++mi) {
                    sreg[g][mi] = __builtin_amdgcn_mfma_f32_16x16x32_bf16(kf[mi][0], qf[g][0], sreg[g][mi], 0, 0, 0);
                    sreg[g][mi] = __builtin_amdgcn_mfma_f32_16x16x32_bf16(kf[mi][1], qf[g][1], sreg[g][mi], 0, 0, 0);
                }
            }

            bf16x8 pfrag[2][2];
#pragma unroll
            for (int g = 0; g < 2; ++g) {
                if (g == 0 && skip0) continue;
                if (!allv) {
#pragma unroll
                    for (int mi = 0; mi < 4; ++mi) {
                        F4 m4; m4.v = *(const float4*)&mk[mi * 16 + quad * 4];
#pragma unroll
                        for (int r = 0; r < 4; ++r) sreg[g][mi][r] += m4.f[r];
                    }
                }
                if (kt == 2 * qt + g) {   // diagonal tile for this group
#pragma unroll
                    for (int mi = 0; mi < 4; ++mi)
#pragma unroll
                        for (int r = 0; r < 4; ++r)
                            if (mi * 16 + quad * 4 + r > wave * 16 + l)
                                sreg[g][mi][r] = NEG_INF;
                }
                // online softmax (per-lane: one query's 16 keys; 2 shfl levels)
                float mloc = sreg[g][0][0];
#pragma unroll
                for (int mi = 0; mi < 4; ++mi)
#pragma unroll
                    for (int r = 0; r < 4; ++r) mloc = fmaxf(mloc, sreg[g][mi][r]);
                mloc = fmaxf(mloc, __shfl_xor(mloc, 16, 64));
                mloc = fmaxf(mloc, __shfl_xor(mloc, 32, 64));
                const float mn = fmaxf(m_run[g], mloc);
                const float alpha = __builtin_amdgcn_exp2f(m_run[g] - mn);
                m_run[g] = mn;
                float ls = 0.0f;
#pragma unroll
                for (int mi = 0; mi < 4; ++mi)
#pragma unroll
                    for (int r = 0; r < 4; ++r) {
                        const float p = __builtin_amdgcn_exp2f(sreg[g][mi][r] - mn);
                        sreg[g][mi][r] = p;
                        ls += p;
                    }
                ls += __shfl_xor(ls, 16, 64);
                ls += __shfl_xor(ls, 32, 64);
                l_run[g] = l_run[g] * alpha + ls;
#pragma unroll
                for (int mi = 0; mi < 4; ++mi)
#pragma unroll
                    for (int r = 0; r < 4; ++r) acc[g][mi][r] *= alpha;

                unsigned pk[4][2];
#pragma unroll
                for (int mi = 0; mi < 4; ++mi) {
                    U2 w0; w0.h[0] = (bf16)sreg[g][mi][0]; w0.h[1] = (bf16)sreg[g][mi][1];
                    U2 w1; w1.h[0] = (bf16)sreg[g][mi][2]; w1.h[1] = (bf16)sreg[g][mi][3];
                    pk[mi][0] = w0.u; pk[mi][1] = w1.u;
                }
#pragma unroll
                for (int kc = 0; kc < 2; ++kc) {
                    U8 u;
#pragma unroll
                    for (int t = 0; t < 2; ++t) {
                        const unsigned a0 = (unsigned)__shfl((int)pk[2 * kc][t],     srcA, 64);
                        const unsigned b0 = (unsigned)__shfl((int)pk[2 * kc + 1][t], srcA, 64);
                        u.u[t] = qh ? b0 : a0;
                        const unsigned a1 = (unsigned)__shfl((int)pk[2 * kc][t],     srcB, 64);
                        const unsigned b1 = (unsigned)__shfl((int)pk[2 * kc + 1][t], srcB, 64);
                        u.u[2 + t] = qh ? b1 : a1;
                    }
                    pfrag[g][kc] = u.v;
                }
            }

            // V frags read ONCE, used by both groups: O^T += V^T · P^T
            bf16x8 vf[4][2];
#pragma unroll
            for (int mi = 0; mi < 4; ++mi) {
                vf[mi][0] = *(const bf16x8*)&Vt[buf][mi * 16 + l][quad * 8];
                vf[mi][1] = *(const bf16x8*)&Vt[buf][mi * 16 + l][32 + quad * 8];
            }
#pragma unroll
            for (int g = 0; g < 2; ++g) {
                if (g == 0 && skip0) continue;
#pragma unroll
                for (int mi = 0; mi < 4; ++mi) {
                    acc[g][mi] = __builtin_amdgcn_mfma_f32_16x16x32_bf16(vf[mi][0], pfrag[g][0], acc[g][mi], 0, 0, 0);
                    acc[g][mi] = __builtin_amdgcn_mfma_f32_16x16x32_bf16(vf[mi][1], pfrag[g][1], acc[g][mi], 0, 0, 0);
                }
            }

            // ---- write prefetched tile into the other buffer ----
            if (more) {
                const int nb = buf ^ 1;
                *(bf16x8*)&Ks[nb][kr][ks]     = kp0;
                *(bf16x8*)&Ks[nb][kr][ks + 8] = kp1;
#pragma unroll
                for (int i = 0; i < 8; ++i) {
                    U2 w; w.h[0] = vp0[i]; w.h[1] = vp1[i];
                    *(unsigned*)&Vt[nb][vds + i][vk0] = w.u;
                }
                if (wave == 0) {
                    mk[nb * 64 + lane] = mv ? 0.0f : NEG_INF;
                    unsigned long long bal = __ballot(mv != 0);
                    if (lane == 0) flagv[nb] = (bal == ~0ULL);
                }
            }
            __syncthreads();
            buf ^= 1;
        }

        // epilogue: Os[q = g*64 + wave*16 + l][d], then coalesced store
#pragma unroll
        for (int g = 0; g < 2; ++g) {
            const float rinv = 1.0f / l_run[g];
#pragma unroll
            for (int mi = 0; mi < 4; ++mi) {
                U2 w0; w0.h[0] = (bf16)(acc[g][mi][0] * rinv); w0.h[1] = (bf16)(acc[g][mi][1] * rinv);
                U2 w1; w1.h[0] = (bf16)(acc[g][mi][2] * rinv); w1.h[1] = (bf16)(acc[g][mi][3] * rinv);
                *(unsigned*)&Os[g * 64 + wave * 16 + l][mi * 16 + quad * 4]     = w0.u;
                *(unsigned*)&Os[g * 64 + wave * 16 + l][mi * 16 + quad * 4 + 2] = w1.u;
            }
        }
        __syncthreads();
        {
            const int orow = tid >> 1, oseg = (tid & 1) * 32;
            bf16* Og = O + (size_t)(b * S_LEN + qt * 128 + orow) * DMODEL + h * HDIM + oseg;
            *(bf16x8*)(Og)      = *(const bf16x8*)&Os[orow][oseg];
            *(bf16x8*)(Og + 8)  = *(const bf16x8*)&Os[orow][oseg + 8];
            *(bf16x8*)(Og + 16) = *(const bf16x8*)&Os[orow][oseg + 16];
            *(bf16x8*)(Og + 24) = *(const bf16x8*)&Os[orow][oseg + 24];
        }
    }
}

// ---------------- launcher ----------------
extern "C" void kernel_launch(void* const* d_in, const int* in_sizes, int n_in,
                              void* d_out, int out_size, void* d_ws, size_t ws_size,
                              hipStream_t stream) {
    const float* x     = (const float*)d_in[0];
    const int*   amask = (const int*)  d_in[1];
    const float* ln1_g = (const float*)d_in[2];
    const float* ln1_b = (const float*)d_in[3];
    const float* ln2_g = (const float*)d_in[4];
    const float* ln2_b = (const float*)d_in[5];
    const float* Wq = (const float*)d_in[6];  const float* bq = (const float*)d_in[7];
    const float* Wk = (const float*)d_in[8];  const float* bk = (const float*)d_in[9];
    const float* Wv = (const float*)d_in[10]; const float* bv = (const float*)d_in[11];
    const float* Wo = (const float*)d_in[12]; const float* bo = (const float*)d_in[13];
    const float* W1 = (const float*)d_in[14]; const float* b1 = (const float*)d_in[15];
    const float* W2 = (const float*)d_in[16]; const float* b2 = (const float*)d_in[17];
    float* out = (float*)d_out;

    char* ws = (char*)d_ws;
    const size_t WSML = (size_t)DMODEL * DMODEL * 2;
    const size_t WBIG = (size_t)DMODEL * DFF_ * 2;
    bf16* Wqt = (bf16*)(ws + 0 * WSML);
    bf16* Wkt = (bf16*)(ws + 1 * WSML);
    bf16* Wvt = (bf16*)(ws + 2 * WSML);
    bf16* Wot = (bf16*)(ws + 3 * WSML);
    bf16* W1t = (bf16*)(ws + 4 * WSML);
    bf16* W2t = (bf16*)(ws + 4 * WSML + WBIG);
    char* act = ws + 4 * WSML + 2 * WBIG;

    const size_t HB = (size_t)MROWS * DMODEL * 2;   // bf16 activation
    const size_t FB = (size_t)MROWS * DMODEL * 4;   // fp32 activation
    bf16*  h    = (bf16*)(act);            // LN1 out; later ctx; later h2
    bf16*  qb   = (bf16*)(act + HB);
    bf16*  kb   = (bf16*)(act + 2 * HB);
    bf16*  vb   = (bf16*)(act + 3 * HB);
    bf16*  ctx  = h;
    float* x1   = (float*)(act + 4 * HB);
    bf16*  f    = (bf16*)(act + 4 * HB + FB);
    bf16*  h2   = h;

    const float SCL = 0.125f * 1.44269504089f;  // 1/sqrt(64) * log2(e), folded into Q

    // 0. weight transpose+convert
    wtrans_kernel<<<dim3(DMODEL / 64, DMODEL / 64), 256, 0, stream>>>(Wq, Wqt, DMODEL, DMODEL);
    wtrans_kernel<<<dim3(DMODEL / 64, DMODEL / 64), 256, 0, stream>>>(Wk, Wkt, DMODEL, DMODEL);
    wtrans_kernel<<<dim3(DMODEL / 64, DMODEL / 64), 256, 0, stream>>>(Wv, Wvt, DMODEL, DMODEL);
    wtrans_kernel<<<dim3(DMODEL / 64, DMODEL / 64), 256, 0, stream>>>(Wo, Wot, DMODEL, DMODEL);
    wtrans_kernel<<<dim3(DFF_ / 64, DMODEL / 64), 256, 0, stream>>>(W1, W1t, DMODEL, DFF_);
    wtrans_kernel<<<dim3(DMODEL / 64, DFF_ / 64), 256, 0, stream>>>(W2, W2t, DFF_, DMODEL);

    // 1. LN1 -> h (bf16)
    ln_kernel<bf16><<<MROWS, 256, 0, stream>>>(x, ln1_g, ln1_b, h);
    // 2. QKV fused, bf16 out; Q pre-scaled by SCL  (1152 blocks)
    mgemm_kernel<128, false, false, true><<<dim3(DMODEL / 128, MROWS / 128, 3), 256, 0, stream>>>(
        h, Wqt, bq, qb, Wkt, bk, kb, Wvt, bv, vb, nullptr, MROWS, DMODEL, DMODEL,
        SCL, 1.0f, 1.0f);
    // 3. transposed-S MFMA flash attention, Br=128 -> ctx (bf16)  (384 uniform blocks)
    mattn_kernel<<<dim3(16, NHEAD, 2), 256, 0, stream>>>(qb, kb, vb, amask, ctx);
    // 4. out proj + residual(x) -> x1 (fp32)  (MT=64: 768 blocks)
    mgemm_kernel<64, false, true, false><<<dim3(DMODEL / 128, MROWS / 64, 1), 256, 0, stream>>>(
        ctx, Wot, bo, x1, Wot, bo, x1, Wot, bo, x1, x, MROWS, DMODEL, DMODEL,
        1.0f, 1.0f, 1.0f);
    // 5. LN2 -> h2 (bf16)
    ln_kernel<bf16><<<MROWS, 256, 0, stream>>>(x1, ln2_g, ln2_b, h2);
    // 6. FF1 + relu -> f (bf16)  (1536 blocks)
    mgemm_kernel<128, true, false, true><<<dim3(DFF_ / 128, MROWS / 128, 1), 256, 0, stream>>>(
        h2, W1t, b1, f, W1t, b1, f, W1t, b1, f, nullptr, MROWS, DFF_, DMODEL,
        1.0f, 1.0f, 1.0f);
    // 7. FF2 + residual(x1) -> out (fp32)  (MT=64: 768 blocks)
    mgemm_kernel<64, false, true, false><<<dim3(DMODEL / 128, MROWS / 64, 1), 256, 0, stream>>>(
        f, W2t, b2, out, W2t, b2, out, W2t, b2, out, x1, MROWS, DMODEL, DFF_,
        1.0f, 1.0f, 1.0f);
}

// Round 8
// 627.397 us; speedup vs baseline: 1.1331x; 1.1331x over previous
//
#include <hip/hip_runtime.h>
#include <hip/hip_bf16.h>
#include <math.h>

#define S_LEN 4096
#define DMODEL 768
#define NHEAD 12
#define HDIM 64
#define DFF_ 3072
#define MROWS 8192  // B*S

typedef __bf16 bf16;
typedef __bf16 bf16x4 __attribute__((ext_vector_type(4)));
typedef __bf16 bf16x8 __attribute__((ext_vector_type(8)));
typedef float f32x4 __attribute__((ext_vector_type(4)));

union F4 { float4 v; float f[4]; };
union U2 { bf16 h[2]; unsigned u; };
union U8 { unsigned u[4]; bf16x8 v; };

__device__ __forceinline__ void gld_lds16(void* lds, const void* g) {
    __builtin_amdgcn_global_load_lds(
        (const __attribute__((address_space(1))) unsigned int*)g,
        (__attribute__((address_space(3))) unsigned int*)lds, 16, 0, 0);
}

// ---------------- LayerNorm ----------------
template<typename OUT>
__global__ __launch_bounds__(256) void ln_kernel(const float* __restrict__ x,
                                                 const float* __restrict__ g,
                                                 const float* __restrict__ bta,
                                                 OUT* __restrict__ out) {
    const int row = blockIdx.x;
    const int t = threadIdx.x;
    const float* xr = x + (size_t)row * DMODEL;
    float v0 = xr[t], v1 = xr[t + 256], v2 = xr[t + 512];
    float s = v0 + v1 + v2;
    float ss = v0 * v0 + v1 * v1 + v2 * v2;
    for (int o = 32; o > 0; o >>= 1) {
        s += __shfl_down(s, o, 64);
        ss += __shfl_down(ss, o, 64);
    }
    __shared__ float sm[4], sm2[4];
    const int w = t >> 6, lane = t & 63;
    if (lane == 0) { sm[w] = s; sm2[w] = ss; }
    __syncthreads();
    s = sm[0] + sm[1] + sm[2] + sm[3];
    ss = sm2[0] + sm2[1] + sm2[2] + sm2[3];
    const float mu = s * (1.0f / DMODEL);
    const float var = ss * (1.0f / DMODEL) - mu * mu;
    const float rs = rsqrtf(var + 1e-5f);
    OUT* orow = out + (size_t)row * DMODEL;
    orow[t]       = (OUT)((v0 - mu) * rs * g[t]       + bta[t]);
    orow[t + 256] = (OUT)((v1 - mu) * rs * g[t + 256] + bta[t + 256]);
    orow[t + 512] = (OUT)((v2 - mu) * rs * g[t + 512] + bta[t + 512]);
}

// ---------------- weight transpose+convert: fp32 [K][N] -> bf16 [N][K] ----------------
__global__ __launch_bounds__(256) void wtrans_kernel(const float* __restrict__ W,
                                                     bf16* __restrict__ Wt,
                                                     int K, int N) {
    __shared__ float tile[64][65];
    const int tid = threadIdx.x;
    const int n0 = blockIdx.x * 64, k0 = blockIdx.y * 64;
    const int lr = tid >> 4, lc = (tid & 15) << 2;
#pragma unroll
    for (int i = 0; i < 4; ++i) {
        const int r = lr + i * 16;
        F4 w; w.v = *(const float4*)&W[(size_t)(k0 + r) * N + n0 + lc];
#pragma unroll
        for (int j = 0; j < 4; ++j) tile[r][lc + j] = w.f[j];
    }
    __syncthreads();
#pragma unroll
    for (int i = 0; i < 4; ++i) {
        const int n = lr + i * 16;
        bf16x4 o;
#pragma unroll
        for (int j = 0; j < 4; ++j) o[j] = (bf16)tile[lc + j][n];
        *(bf16x4*)&Wt[(size_t)(n0 + n) * K + k0 + lc] = o;
    }
}

// ---------------- bf16 MFMA GEMM (m97 structure), MT x 128 tile ----------------
template<int MT, bool RELU, bool RES, bool OUT_BF16>
__global__ __launch_bounds__(256) void mgemm_kernel(
    const bf16* __restrict__ A,
    const bf16* __restrict__ Wt0, const float* __restrict__ bias0, void* __restrict__ C0,
    const bf16* __restrict__ Wt1, const float* __restrict__ bias1, void* __restrict__ C1,
    const bf16* __restrict__ Wt2, const float* __restrict__ bias2, void* __restrict__ C2,
    const float* __restrict__ R, int M, int N, int K,
    float sc0, float sc1, float sc2) {
    const bf16* Wt = Wt0; const float* bias = bias0; void* C = C0; float sc = sc0;
    if (blockIdx.z == 1) { Wt = Wt1; bias = bias1; C = C1; sc = sc1; }
    if (blockIdx.z == 2) { Wt = Wt2; bias = bias2; C = C2; sc = sc2; }

    constexpr int NI = (MT == 128) ? 4 : 2;
    __shared__ bf16 As[MT * 32];
    __shared__ bf16 Bs[128 * 32];

    const int tid = threadIdx.x;
    const int wave = tid >> 6, lane = tid & 63;
    const int row0 = blockIdx.y * MT, col0 = blockIdx.x * 128;
    const int wr = (MT == 128) ? (wave >> 1) * 64 : 0;
    const int wc = (MT == 128) ? (wave & 1) * 64 : wave * 32;
    const int mrow = lane & 15, kq = (lane >> 4) * 8;

    const int st_row = (lane >> 2);
    const int st_off = (lane & 3) * 16;

    f32x4 acc[4][NI] = {};

    const char* Ab = (const char*)(A + (size_t)row0 * K);
    const char* Bb = (const char*)(Wt + (size_t)col0 * K);
    const size_t strideA = (size_t)K * 2;

    for (int k0 = 0; k0 < K; k0 += 32) {
        if (MT == 128) {
#pragma unroll
            for (int issue = 0; issue < 2; ++issue) {
                const int r = wave * 32 + issue * 16 + st_row;
                gld_lds16((char*)As + (wave * 32 + issue * 16) * 64,
                          Ab + (size_t)r * strideA + k0 * 2 + st_off);
            }
        } else {
            const int r = wave * 16 + st_row;
            gld_lds16((char*)As + (wave * 16) * 64,
                      Ab + (size_t)r * strideA + k0 * 2 + st_off);
        }
#pragma unroll
        for (int issue = 0; issue < 2; ++issue) {
            const int r = wave * 32 + issue * 16 + st_row;
            gld_lds16((char*)Bs + (wave * 32 + issue * 16) * 64,
                      Bb + (size_t)r * strideA + k0 * 2 + st_off);
        }
        __syncthreads();
        bf16x8 af[4], bfr[NI];
#pragma unroll
        for (int mi = 0; mi < 4; ++mi)
            af[mi] = *(const bf16x8*)&As[(wr + mi * 16 + mrow) * 32 + kq];
#pragma unroll
        for (int ni = 0; ni < NI; ++ni)
            bfr[ni] = *(const bf16x8*)&Bs[(wc + ni * 16 + mrow) * 32 + kq];
#pragma unroll
        for (int mi = 0; mi < 4; ++mi)
#pragma unroll
            for (int ni = 0; ni < NI; ++ni)
                acc[mi][ni] = __builtin_amdgcn_mfma_f32_16x16x32_bf16(
                    af[mi], bfr[ni], acc[mi][ni], 0, 0, 0);
        __syncthreads();
    }

    const int quad = lane >> 4;
    float bv[NI];
#pragma unroll
    for (int ni = 0; ni < NI; ++ni) bv[ni] = bias[col0 + wc + ni * 16 + mrow];
#pragma unroll
    for (int mi = 0; mi < 4; ++mi) {
#pragma unroll
        for (int r = 0; r < 4; ++r) {
            const int row = row0 + wr + mi * 16 + quad * 4 + r;
#pragma unroll
            for (int ni = 0; ni < NI; ++ni) {
                const int col = col0 + wc + ni * 16 + mrow;
                float v = acc[mi][ni][r] + bv[ni];
                if (RES) v += R[(size_t)row * N + col];
                v *= sc;
                if (RELU) v = fmaxf(v, 0.0f);
                if (OUT_BF16) ((bf16*)C)[(size_t)row * N + col] = (bf16)v;
                else          ((float*)C)[(size_t)row * N + col] = v;
            }
        }
    }
}

// ---------------- Split-K transposed-S MFMA flash attention, Br=128 ----------------
// Each wave serves 32 queries (2 groups of 16) per K/V LDS frag read set.
// Key range of each 128-query tile is split into two half-jobs of (qt+1)
// key-tiles each (diagonal in half 1). Block = 2 paired half-jobs (bx, 63-bx)
// -> 768 blocks x uniform 33 iters, 3 blocks/CU co-resident (LDS 35.4 KB).
// Jobs emit unnormalized bf16 partials + per-query (m,l); combine kernel merges.
// -1e30 soft -inf keeps fully-masked groups NaN-free.
__global__ __launch_bounds__(256, 3) void mattn_kernel(
    const bf16* __restrict__ Q, const bf16* __restrict__ K,
    const bf16* __restrict__ V, const int* __restrict__ amask,
    bf16* __restrict__ Opart, float2* __restrict__ mlb) {
    const int bx = blockIdx.x, h = blockIdx.y, b = blockIdx.z;

    __shared__ __align__(16) char smem[2 * 17408 + 512 + 16];
    typedef bf16 Tile[64][68];                       // 8704 B per tile
    Tile* Ks = (Tile*)smem;                          // Ks[buf][key][d]
    Tile* Vt = (Tile*)(smem + 17408);                // Vt[buf][d][key]
    float* mk = (float*)(smem + 34816);              // [2][64]
    int* flagv = (int*)(smem + 34816 + 512);         // [2]
    bf16 (*Os)[68] = (bf16(*)[68])smem;              // [128][68] alias of Ks

    const int tid = threadIdx.x;
    const int wave = tid >> 6, lane = tid & 63;
    const int l = lane & 15, quad = lane >> 4;
    const int qh = quad >> 1;
    const int srcA = (quad & 1) * 32 + l;
    const int srcB = srcA + 16;
    const float SNEG = -1e30f;   // soft -inf (NaN-free online softmax)

    const int kr = tid >> 2, ks = (tid & 3) * 16;          // K tile staging
    const int vk0 = (tid & 31) * 2, vds = (tid >> 5) * 8;  // V transpose staging

    const bf16* Kbase = K + (size_t)b * S_LEN * DMODEL + h * HDIM;
    const bf16* Vbase = V + (size_t)b * S_LEN * DMODEL + h * HDIM;

#pragma unroll 1
    for (int pass = 0; pass < 2; ++pass) {
        const int jidx = pass ? (63 - bx) : bx;
        const int qt = jidx >> 1, half = jidx & 1;   // q-tile of 128 queries
        const int nt = qt + 1;                        // key-tiles in this half
        const int kbase = half ? (qt + 1) : 0;        // first absolute key-tile
        const size_t jid = ((size_t)(b * NHEAD + h) * 32 + qt) * 2 + half;

        // Q fragments (B-operand) for both q-groups, pre-scaled, in registers
        bf16x8 qf[2][2];
#pragma unroll
        for (int g = 0; g < 2; ++g) {
            const bf16* Qb = Q + (size_t)(b * S_LEN + qt * 128 + g * 64 + wave * 16 + l) * DMODEL + h * HDIM;
            qf[g][0] = *(const bf16x8*)(Qb + quad * 8);
            qf[g][1] = *(const bf16x8*)(Qb + 32 + quad * 8);
        }

        float m_run[2] = {SNEG, SNEG}, l_run[2] = {0.0f, 0.0f};
        f32x4 acc[2][4] = {};

        // ---- prefetch first tile into registers ----
        bf16x8 kp0, kp1, vp0, vp1;
        int mv = 1;
        {
            const bf16* kg = Kbase + (size_t)(kbase * 64 + kr) * DMODEL + ks;
            kp0 = *(const bf16x8*)kg;
            kp1 = *(const bf16x8*)(kg + 8);
            const bf16* vg = Vbase + (size_t)(kbase * 64 + vk0) * DMODEL + vds;
            vp0 = *(const bf16x8*)vg;
            vp1 = *(const bf16x8*)(vg + DMODEL);
            if (wave == 0) mv = amask[b * S_LEN + kbase * 64 + lane];
        }
        __syncthreads();   // prior pass epilogue LDS reads complete
        {
            *(bf16x8*)&Ks[0][kr][ks]     = kp0;
            *(bf16x8*)&Ks[0][kr][ks + 8] = kp1;
#pragma unroll
            for (int i = 0; i < 8; ++i) {
                U2 w; w.h[0] = vp0[i]; w.h[1] = vp1[i];
                *(unsigned*)&Vt[0][vds + i][vk0] = w.u;
            }
            if (wave == 0) {
                mk[lane] = mv ? 0.0f : SNEG;
                unsigned long long bal = __ballot(mv != 0);
                if (lane == 0) flagv[0] = (bal == ~0ULL);
            }
        }
        __syncthreads();
        int buf = 0;

        for (int j = 0; j < nt; ++j) {
            const int kta = kbase + j;               // absolute key-tile
            const bool more = (j + 1 < nt);
            if (more) {   // issue next tile's global loads
                const bf16* kg = Kbase + (size_t)((kta + 1) * 64 + kr) * DMODEL + ks;
                kp0 = *(const bf16x8*)kg;
                kp1 = *(const bf16x8*)(kg + 8);
                const bf16* vg = Vbase + (size_t)((kta + 1) * 64 + vk0) * DMODEL + vds;
                vp0 = *(const bf16x8*)vg;
                vp1 = *(const bf16x8*)(vg + DMODEL);
                if (wave == 0) mv = amask[b * S_LEN + (kta + 1) * 64 + lane];
            }

            const int allv = flagv[buf];
            const bool skip0 = (kta == 2 * qt + 1);  // group 0 fully masked

            // K frags read ONCE, used by both q-groups
            bf16x8 kf[4][2];
#pragma unroll
            for (int mi = 0; mi < 4; ++mi) {
                kf[mi][0] = *(const bf16x8*)&Ks[buf][mi * 16 + l][quad * 8];
                kf[mi][1] = *(const bf16x8*)&Ks[buf][mi * 16 + l][32 + quad * 8];
            }
            f32x4 sreg[2][4] = {};
#pragma unroll
            for (int g = 0; g < 2; ++g) {
                if (g == 0 && skip0) continue;
#pragma unroll
                for (int mi = 0; mi < 4; ++mi) {
                    sreg[g][mi] = __builtin_amdgcn_mfma_f32_16x16x32_bf16(kf[mi][0], qf[g][0], sreg[g][mi], 0, 0, 0);
                    sreg[g][mi] = __builtin_amdgcn_mfma_f32_16x16x32_bf16(kf[mi][1], qf[g][1], sreg[g][mi], 0, 0, 0);
                }
            }

            bf16x8 pfrag[2][2];
#pragma unroll
            for (int g = 0; g < 2; ++g) {
                if (g == 0 && skip0) continue;
                if (!allv) {
#pragma unroll
                    for (int mi = 0; mi < 4; ++mi) {
                        F4 m4; m4.v = *(const float4*)&mk[mi * 16 + quad * 4];
#pragma unroll
                        for (int r = 0; r < 4; ++r) sreg[g][mi][r] += m4.f[r];
                    }
                }
                if (kta == 2 * qt + g) {   // diagonal tile for this group
#pragma unroll
                    for (int mi = 0; mi < 4; ++mi)
#pragma unroll
                        for (int r = 0; r < 4; ++r)
                            if (mi * 16 + quad * 4 + r > wave * 16 + l)
                                sreg[g][mi][r] = SNEG;
                }
                // online softmax (per-lane: one query's 16 keys; 2 shfl levels)
                float mloc = sreg[g][0][0];
#pragma unroll
                for (int mi = 0; mi < 4; ++mi)
#pragma unroll
                    for (int r = 0; r < 4; ++r) mloc = fmaxf(mloc, sreg[g][mi][r]);
                mloc = fmaxf(mloc, __shfl_xor(mloc, 16, 64));
                mloc = fmaxf(mloc, __shfl_xor(mloc, 32, 64));
                const float mn = fmaxf(m_run[g], mloc);
                const float alpha = __builtin_amdgcn_exp2f(m_run[g] - mn);
                m_run[g] = mn;
                float ls = 0.0f;
#pragma unroll
                for (int mi = 0; mi < 4; ++mi)
#pragma unroll
                    for (int r = 0; r < 4; ++r) {
                        const float p = __builtin_amdgcn_exp2f(sreg[g][mi][r] - mn);
                        sreg[g][mi][r] = p;
                        ls += p;
                    }
                ls += __shfl_xor(ls, 16, 64);
                ls += __shfl_xor(ls, 32, 64);
                l_run[g] = l_run[g] * alpha + ls;
#pragma unroll
                for (int mi = 0; mi < 4; ++mi)
#pragma unroll
                    for (int r = 0; r < 4; ++r) acc[g][mi][r] *= alpha;

                unsigned pk[4][2];
#pragma unroll
                for (int mi = 0; mi < 4; ++mi) {
                    U2 w0; w0.h[0] = (bf16)sreg[g][mi][0]; w0.h[1] = (bf16)sreg[g][mi][1];
                    U2 w1; w1.h[0] = (bf16)sreg[g][mi][2]; w1.h[1] = (bf16)sreg[g][mi][3];
                    pk[mi][0] = w0.u; pk[mi][1] = w1.u;
                }
#pragma unroll
                for (int kc = 0; kc < 2; ++kc) {
                    U8 u;
#pragma unroll
                    for (int t = 0; t < 2; ++t) {
                        const unsigned a0 = (unsigned)__shfl((int)pk[2 * kc][t],     srcA, 64);
                        const unsigned b0 = (unsigned)__shfl((int)pk[2 * kc + 1][t], srcA, 64);
                        u.u[t] = qh ? b0 : a0;
                        const unsigned a1 = (unsigned)__shfl((int)pk[2 * kc][t],     srcB, 64);
                        const unsigned b1 = (unsigned)__shfl((int)pk[2 * kc + 1][t], srcB, 64);
                        u.u[2 + t] = qh ? b1 : a1;
                    }
                    pfrag[g][kc] = u.v;
                }
            }

            // V frags read ONCE, used by both groups: O^T += V^T · P^T
            bf16x8 vf[4][2];
#pragma unroll
            for (int mi = 0; mi < 4; ++mi) {
                vf[mi][0] = *(const bf16x8*)&Vt[buf][mi * 16 + l][quad * 8];
                vf[mi][1] = *(const bf16x8*)&Vt[buf][mi * 16 + l][32 + quad * 8];
            }
#pragma unroll
            for (int g = 0; g < 2; ++g) {
                if (g == 0 && skip0) continue;
#pragma unroll
                for (int mi = 0; mi < 4; ++mi) {
                    acc[g][mi] = __builtin_amdgcn_mfma_f32_16x16x32_bf16(vf[mi][0], pfrag[g][0], acc[g][mi], 0, 0, 0);
                    acc[g][mi] = __builtin_amdgcn_mfma_f32_16x16x32_bf16(vf[mi][1], pfrag[g][1], acc[g][mi], 0, 0, 0);
                }
            }

            // ---- write prefetched tile into the other buffer ----
            if (more) {
                const int nb = buf ^ 1;
                *(bf16x8*)&Ks[nb][kr][ks]     = kp0;
                *(bf16x8*)&Ks[nb][kr][ks + 8] = kp1;
#pragma unroll
                for (int i = 0; i < 8; ++i) {
                    U2 w; w.h[0] = vp0[i]; w.h[1] = vp1[i];
                    *(unsigned*)&Vt[nb][vds + i][vk0] = w.u;
                }
                if (wave == 0) {
                    mk[nb * 64 + lane] = mv ? 0.0f : SNEG;
                    unsigned long long bal = __ballot(mv != 0);
                    if (lane == 0) flagv[nb] = (bal == ~0ULL);
                }
            }
            __syncthreads();
            buf ^= 1;
        }

        // ---- epilogue: store UNNORMALIZED partial (bf16) + (m,l) per query ----
#pragma unroll
        for (int g = 0; g < 2; ++g) {
#pragma unroll
            for (int mi = 0; mi < 4; ++mi) {
                U2 w0; w0.h[0] = (bf16)acc[g][mi][0]; w0.h[1] = (bf16)acc[g][mi][1];
                U2 w1; w1.h[0] = (bf16)acc[g][mi][2]; w1.h[1] = (bf16)acc[g][mi][3];
                *(unsigned*)&Os[g * 64 + wave * 16 + l][mi * 16 + quad * 4]     = w0.u;
                *(unsigned*)&Os[g * 64 + wave * 16 + l][mi * 16 + quad * 4 + 2] = w1.u;
            }
        }
        if (quad == 0) {
            mlb[jid * 128 + wave * 16 + l]      = make_float2(m_run[0], l_run[0]);
            mlb[jid * 128 + 64 + wave * 16 + l] = make_float2(m_run[1], l_run[1]);
        }
        __syncthreads();
        {   // coalesced partial store: [jid][q][d], 64 B per thread
            const int orow = tid >> 1, oseg = (tid & 1) * 32;
            bf16* Og = Opart + jid * 8192 + orow * 64 + oseg;
            *(bf16x8*)(Og)      = *(const bf16x8*)&Os[orow][oseg];
            *(bf16x8*)(Og + 8)  = *(const bf16x8*)&Os[orow][oseg + 8];
            *(bf16x8*)(Og + 16) = *(const bf16x8*)&Os[orow][oseg + 16];
            *(bf16x8*)(Og + 24) = *(const bf16x8*)&Os[orow][oseg + 24];
        }
    }
}

// ---------------- combine: merge the two half-job partials per q-tile ----------------
__global__ __launch_bounds__(256) void attn_combine_kernel(
    const bf16* __restrict__ Opart, const float2* __restrict__ mlb,
    bf16* __restrict__ O) {
    const int qt = blockIdx.x, h = blockIdx.y, b = blockIdx.z;
    const size_t base = ((size_t)(b * NHEAD + h) * 32 + qt) * 2;
    const int tid = threadIdx.x;
    const int q = tid >> 1, seg = (tid & 1) * 32;
    const float2 a = mlb[base * 128 + q];
    const float2 c = mlb[(base + 1) * 128 + q];
    const float m = fmaxf(a.x, c.x);
    float wA = exp2f(a.x - m), wB = exp2f(c.x - m);
    const float rin = 1.0f / (wA * a.y + wB * c.y);
    wA *= rin; wB *= rin;
    const bf16* pa = Opart + base * 8192 + q * 64 + seg;
    const bf16* pb = Opart + (base + 1) * 8192 + q * 64 + seg;
    bf16* og = O + (size_t)(b * S_LEN + qt * 128 + q) * DMODEL + h * HDIM + seg;
#pragma unroll
    for (int c8 = 0; c8 < 4; ++c8) {
        bf16x8 xa = *(const bf16x8*)(pa + c8 * 8);
        bf16x8 xb = *(const bf16x8*)(pb + c8 * 8);
        bf16x8 o;
#pragma unroll
        for (int jj = 0; jj < 8; ++jj)
            o[jj] = (bf16)(wA * (float)xa[jj] + wB * (float)xb[jj]);
        *(bf16x8*)(og + c8 * 8) = o;
    }
}

// ---------------- launcher ----------------
extern "C" void kernel_launch(void* const* d_in, const int* in_sizes, int n_in,
                              void* d_out, int out_size, void* d_ws, size_t ws_size,
                              hipStream_t stream) {
    const float* x     = (const float*)d_in[0];
    const int*   amask = (const int*)  d_in[1];
    const float* ln1_g = (const float*)d_in[2];
    const float* ln1_b = (const float*)d_in[3];
    const float* ln2_g = (const float*)d_in[4];
    const float* ln2_b = (const float*)d_in[5];
    const float* Wq = (const float*)d_in[6];  const float* bq = (const float*)d_in[7];
    const float* Wk = (const float*)d_in[8];  const float* bk = (const float*)d_in[9];
    const float* Wv = (const float*)d_in[10]; const float* bv = (const float*)d_in[11];
    const float* Wo = (const float*)d_in[12]; const float* bo = (const float*)d_in[13];
    const float* W1 = (const float*)d_in[14]; const float* b1 = (const float*)d_in[15];
    const float* W2 = (const float*)d_in[16]; const float* b2 = (const float*)d_in[17];
    float* out = (float*)d_out;

    char* ws = (char*)d_ws;
    const size_t WSML = (size_t)DMODEL * DMODEL * 2;
    const size_t WBIG = (size_t)DMODEL * DFF_ * 2;
    bf16* Wqt = (bf16*)(ws + 0 * WSML);
    bf16* Wkt = (bf16*)(ws + 1 * WSML);
    bf16* Wvt = (bf16*)(ws + 2 * WSML);
    bf16* Wot = (bf16*)(ws + 3 * WSML);
    bf16* W1t = (bf16*)(ws + 4 * WSML);
    bf16* W2t = (bf16*)(ws + 4 * WSML + WBIG);
    char* act = ws + 4 * WSML + 2 * WBIG;

    const size_t HB = (size_t)MROWS * DMODEL * 2;   // bf16 activation
    const size_t FB = (size_t)MROWS * DMODEL * 4;   // fp32 activation
    bf16*  h    = (bf16*)(act);            // LN1 out; later ctx; later h2
    bf16*  qb   = (bf16*)(act + HB);
    bf16*  kb   = (bf16*)(act + 2 * HB);
    bf16*  vb   = (bf16*)(act + 3 * HB);
    bf16*  ctx  = h;
    float* x1   = (float*)(act + 4 * HB);
    bf16*  f    = (bf16*)(act + 4 * HB + FB);
    bf16*  h2   = h;
    // attention partials live in the (currently dead) FF scratch region
    bf16*   opart = f;                                           // 1536*8192*2 B = 25.2 MB
    float2* mlb   = (float2*)(act + 4 * HB + FB + (size_t)1536 * 8192 * 2);  // 1.6 MB

    const float SCL = 0.125f * 1.44269504089f;  // 1/sqrt(64) * log2(e), folded into Q

    // 0. weight transpose+convert
    wtrans_kernel<<<dim3(DMODEL / 64, DMODEL / 64), 256, 0, stream>>>(Wq, Wqt, DMODEL, DMODEL);
    wtrans_kernel<<<dim3(DMODEL / 64, DMODEL / 64), 256, 0, stream>>>(Wk, Wkt, DMODEL, DMODEL);
    wtrans_kernel<<<dim3(DMODEL / 64, DMODEL / 64), 256, 0, stream>>>(Wv, Wvt, DMODEL, DMODEL);
    wtrans_kernel<<<dim3(DMODEL / 64, DMODEL / 64), 256, 0, stream>>>(Wo, Wot, DMODEL, DMODEL);
    wtrans_kernel<<<dim3(DFF_ / 64, DMODEL / 64), 256, 0, stream>>>(W1, W1t, DMODEL, DFF_);
    wtrans_kernel<<<dim3(DMODEL / 64, DFF_ / 64), 256, 0, stream>>>(W2, W2t, DFF_, DMODEL);

    // 1. LN1 -> h (bf16)
    ln_kernel<bf16><<<MROWS, 256, 0, stream>>>(x, ln1_g, ln1_b, h);
    // 2. QKV fused, bf16 out; Q pre-scaled by SCL  (1152 blocks)
    mgemm_kernel<128, false, false, true><<<dim3(DMODEL / 128, MROWS / 128, 3), 256, 0, stream>>>(
        h, Wqt, bq, qb, Wkt, bk, kb, Wvt, bv, vb, nullptr, MROWS, DMODEL, DMODEL,
        SCL, 1.0f, 1.0f);
    // 3. split-K flash attention -> partials  (768 uniform blocks)
    mattn_kernel<<<dim3(32, NHEAD, 2), 256, 0, stream>>>(qb, kb, vb, amask, opart, mlb);
    // 3b. combine halves -> ctx (bf16)  (768 blocks)
    attn_combine_kernel<<<dim3(32, NHEAD, 2), 256, 0, stream>>>(opart, mlb, ctx);
    // 4. out proj + residual(x) -> x1 (fp32)  (MT=64: 768 blocks)
    mgemm_kernel<64, false, true, false><<<dim3(DMODEL / 128, MROWS / 64, 1), 256, 0, stream>>>(
        ctx, Wot, bo, x1, Wot, bo, x1, Wot, bo, x1, x, MROWS, DMODEL, DMODEL,
        1.0f, 1.0f, 1.0f);
    // 5. LN2 -> h2 (bf16)
    ln_kernel<bf16><<<MROWS, 256, 0, stream>>>(x1, ln2_g, ln2_b, h2);
    // 6. FF1 + relu -> f (bf16)  (1536 blocks)  [f overlaps dead partials]
    mgemm_kernel<128, true, false, true><<<dim3(DFF_ / 128, MROWS / 128, 1), 256, 0, stream>>>(
        h2, W1t, b1, f, W1t, b1, f, W1t, b1, f, nullptr, MROWS, DFF_, DMODEL,
        1.0f, 1.0f, 1.0f);
    // 7. FF2 + residual(x1) -> out (fp32)  (MT=64: 768 blocks)
    mgemm_kernel<64, false, true, false><<<dim3(DMODEL / 128, MROWS / 64, 1), 256, 0, stream>>>(
        f, W2t, b2, out, W2t, b2, out, W2t, b2, out, x1, MROWS, DMODEL, DFF_,
        1.0f, 1.0f, 1.0f);
}

// Round 9
// 571.807 us; speedup vs baseline: 1.2432x; 1.0972x over previous
//
#include <hip/hip_runtime.h>
#include <hip/hip_bf16.h>
#include <math.h>

#define S_LEN 4096
#define DMODEL 768
#define NHEAD 12
#define HDIM 64
#define DFF_ 3072
#define MROWS 8192  // B*S

typedef __bf16 bf16;
typedef __bf16 bf16x4 __attribute__((ext_vector_type(4)));
typedef __bf16 bf16x8 __attribute__((ext_vector_type(8)));
typedef float f32x4 __attribute__((ext_vector_type(4)));

union F4 { float4 v; float f[4]; };
union U2 { bf16 h[2]; unsigned u; };
union U8 { unsigned u[4]; bf16x8 v; };

__device__ __forceinline__ void gld_lds16(void* lds, const void* g) {
    __builtin_amdgcn_global_load_lds(
        (const __attribute__((address_space(1))) unsigned int*)g,
        (__attribute__((address_space(3))) unsigned int*)lds, 16, 0, 0);
}

// ---------------- LayerNorm ----------------
template<typename OUT>
__global__ __launch_bounds__(256) void ln_kernel(const float* __restrict__ x,
                                                 const float* __restrict__ g,
                                                 const float* __restrict__ bta,
                                                 OUT* __restrict__ out) {
    const int row = blockIdx.x;
    const int t = threadIdx.x;
    const float* xr = x + (size_t)row * DMODEL;
    float v0 = xr[t], v1 = xr[t + 256], v2 = xr[t + 512];
    float s = v0 + v1 + v2;
    float ss = v0 * v0 + v1 * v1 + v2 * v2;
    for (int o = 32; o > 0; o >>= 1) {
        s += __shfl_down(s, o, 64);
        ss += __shfl_down(ss, o, 64);
    }
    __shared__ float sm[4], sm2[4];
    const int w = t >> 6, lane = t & 63;
    if (lane == 0) { sm[w] = s; sm2[w] = ss; }
    __syncthreads();
    s = sm[0] + sm[1] + sm[2] + sm[3];
    ss = sm2[0] + sm2[1] + sm2[2] + sm2[3];
    const float mu = s * (1.0f / DMODEL);
    const float var = ss * (1.0f / DMODEL) - mu * mu;
    const float rs = rsqrtf(var + 1e-5f);
    OUT* orow = out + (size_t)row * DMODEL;
    orow[t]       = (OUT)((v0 - mu) * rs * g[t]       + bta[t]);
    orow[t + 256] = (OUT)((v1 - mu) * rs * g[t + 256] + bta[t + 256]);
    orow[t + 512] = (OUT)((v2 - mu) * rs * g[t + 512] + bta[t + 512]);
}

// ---------------- fused weight transpose+convert: all 6 weights, one launch ----------------
// W fp32 [K][N] -> Wt bf16 [N][K]; 64x64 tiles, 1728 total.
__global__ __launch_bounds__(256) void wtrans_all_kernel(
    const float* __restrict__ Wq, const float* __restrict__ Wk,
    const float* __restrict__ Wv, const float* __restrict__ Wo,
    const float* __restrict__ W1, const float* __restrict__ W2,
    bf16* __restrict__ Wqt, bf16* __restrict__ Wkt, bf16* __restrict__ Wvt,
    bf16* __restrict__ Wot, bf16* __restrict__ W1t, bf16* __restrict__ W2t) {
    int t = blockIdx.x;
    const float* W; bf16* Wt; int K, N;
    if      (t < 144)  { W = Wq; Wt = Wqt; K = 768;  N = 768;  }
    else if (t < 288)  { W = Wk; Wt = Wkt; K = 768;  N = 768;  t -= 144; }
    else if (t < 432)  { W = Wv; Wt = Wvt; K = 768;  N = 768;  t -= 288; }
    else if (t < 576)  { W = Wo; Wt = Wot; K = 768;  N = 768;  t -= 432; }
    else if (t < 1152) { W = W1; Wt = W1t; K = 768;  N = 3072; t -= 576; }
    else               { W = W2; Wt = W2t; K = 3072; N = 768;  t -= 1152; }
    const int nx = N >> 6;
    const int n0 = (t % nx) * 64, k0 = (t / nx) * 64;

    __shared__ float tile[64][65];
    const int tid = threadIdx.x;
    const int lr = tid >> 4, lc = (tid & 15) << 2;
#pragma unroll
    for (int i = 0; i < 4; ++i) {
        const int r = lr + i * 16;
        F4 w; w.v = *(const float4*)&W[(size_t)(k0 + r) * N + n0 + lc];
#pragma unroll
        for (int j = 0; j < 4; ++j) tile[r][lc + j] = w.f[j];
    }
    __syncthreads();
#pragma unroll
    for (int i = 0; i < 4; ++i) {
        const int n = lr + i * 16;
        bf16x4 o;
#pragma unroll
        for (int j = 0; j < 4; ++j) o[j] = (bf16)tile[lc + j][n];
        *(bf16x4*)&Wt[(size_t)(n0 + n) * K + k0 + lc] = o;
    }
}

// ---------------- bf16 MFMA GEMM (m97 structure), MT x 128 tile ----------------
template<int MT, bool RELU, bool RES, bool OUT_BF16>
__global__ __launch_bounds__(256) void mgemm_kernel(
    const bf16* __restrict__ A,
    const bf16* __restrict__ Wt0, const float* __restrict__ bias0, void* __restrict__ C0,
    const bf16* __restrict__ Wt1, const float* __restrict__ bias1, void* __restrict__ C1,
    const bf16* __restrict__ Wt2, const float* __restrict__ bias2, void* __restrict__ C2,
    const float* __restrict__ R, int M, int N, int K,
    float sc0, float sc1, float sc2) {
    const bf16* Wt = Wt0; const float* bias = bias0; void* C = C0; float sc = sc0;
    if (blockIdx.z == 1) { Wt = Wt1; bias = bias1; C = C1; sc = sc1; }
    if (blockIdx.z == 2) { Wt = Wt2; bias = bias2; C = C2; sc = sc2; }

    constexpr int NI = (MT == 128) ? 4 : 2;
    __shared__ bf16 As[MT * 32];
    __shared__ bf16 Bs[128 * 32];

    const int tid = threadIdx.x;
    const int wave = tid >> 6, lane = tid & 63;
    const int row0 = blockIdx.y * MT, col0 = blockIdx.x * 128;
    const int wr = (MT == 128) ? (wave >> 1) * 64 : 0;
    const int wc = (MT == 128) ? (wave & 1) * 64 : wave * 32;
    const int mrow = lane & 15, kq = (lane >> 4) * 8;

    const int st_row = (lane >> 2);
    const int st_off = (lane & 3) * 16;

    f32x4 acc[4][NI] = {};

    const char* Ab = (const char*)(A + (size_t)row0 * K);
    const char* Bb = (const char*)(Wt + (size_t)col0 * K);
    const size_t strideA = (size_t)K * 2;

    for (int k0 = 0; k0 < K; k0 += 32) {
        if (MT == 128) {
#pragma unroll
            for (int issue = 0; issue < 2; ++issue) {
                const int r = wave * 32 + issue * 16 + st_row;
                gld_lds16((char*)As + (wave * 32 + issue * 16) * 64,
                          Ab + (size_t)r * strideA + k0 * 2 + st_off);
            }
        } else {
            const int r = wave * 16 + st_row;
            gld_lds16((char*)As + (wave * 16) * 64,
                      Ab + (size_t)r * strideA + k0 * 2 + st_off);
        }
#pragma unroll
        for (int issue = 0; issue < 2; ++issue) {
            const int r = wave * 32 + issue * 16 + st_row;
            gld_lds16((char*)Bs + (wave * 32 + issue * 16) * 64,
                      Bb + (size_t)r * strideA + k0 * 2 + st_off);
        }
        __syncthreads();
        bf16x8 af[4], bfr[NI];
#pragma unroll
        for (int mi = 0; mi < 4; ++mi)
            af[mi] = *(const bf16x8*)&As[(wr + mi * 16 + mrow) * 32 + kq];
#pragma unroll
        for (int ni = 0; ni < NI; ++ni)
            bfr[ni] = *(const bf16x8*)&Bs[(wc + ni * 16 + mrow) * 32 + kq];
#pragma unroll
        for (int mi = 0; mi < 4; ++mi)
#pragma unroll
            for (int ni = 0; ni < NI; ++ni)
                acc[mi][ni] = __builtin_amdgcn_mfma_f32_16x16x32_bf16(
                    af[mi], bfr[ni], acc[mi][ni], 0, 0, 0);
        __syncthreads();
    }

    const int quad = lane >> 4;
    float bv[NI];
#pragma unroll
    for (int ni = 0; ni < NI; ++ni) bv[ni] = bias[col0 + wc + ni * 16 + mrow];
#pragma unroll
    for (int mi = 0; mi < 4; ++mi) {
#pragma unroll
        for (int r = 0; r < 4; ++r) {
            const int row = row0 + wr + mi * 16 + quad * 4 + r;
#pragma unroll
            for (int ni = 0; ni < NI; ++ni) {
                const int col = col0 + wc + ni * 16 + mrow;
                float v = acc[mi][ni][r] + bv[ni];
                if (RES) v += R[(size_t)row * N + col];
                v *= sc;
                if (RELU) v = fmaxf(v, 0.0f);
                if (OUT_BF16) ((bf16*)C)[(size_t)row * N + col] = (bf16)v;
                else          ((float*)C)[(size_t)row * N + col] = v;
            }
        }
    }
}

// ---------------- Transposed-S MFMA flash attention (R6 structure, 4 blocks/CU) ----------------
// S^T = K·Q^T (lane's C-column = fixed query q = lane&15); P^T re-layout via
// quad-level shfl (no LDS round trip). Q pre-scaled by 0.125*log2(e).
// Double-buffered K/V, 1 barrier/iter. Epilogue bounce aliases Ks -> LDS
// 35.3 KB -> 4 blocks/CU. grid (64,H,B) = 1536 blocks, heavy-first: 6/CU
// demand over 4 resident slots gives LPT-style backfill.
__global__ __launch_bounds__(256, 4) void mattn_kernel(
    const bf16* __restrict__ Q, const bf16* __restrict__ K,
    const bf16* __restrict__ V, const int* __restrict__ amask,
    bf16* __restrict__ O) {
    const int qt = 63 - blockIdx.x;  // heavy tiles first
    const int h = blockIdx.y, b = blockIdx.z;

    __shared__ bf16 Ks[2][64][68];   // [buf][key][d]  (136 B rows: conflict-free)
    __shared__ bf16 Vt[2][64][68];   // [buf][d][key]
    __shared__ float mk[2][64];
    __shared__ int flagv[2];
    bf16 (*Os)[68] = Ks[0];          // epilogue bounce aliases Ks (safe after final barrier)

    const int tid = threadIdx.x;
    const int wave = tid >> 6, lane = tid & 63;
    const int l = lane & 15, quad = lane >> 4;
    const int qh = quad >> 1;
    const int srcA = (quad & 1) * 32 + l;
    const int srcB = srcA + 16;
    const float NEG_INF = -__builtin_huge_valf();

    const int kr = tid >> 2, ks = (tid & 3) * 16;          // K tile staging
    const int vk0 = (tid & 31) * 2, vds = (tid >> 5) * 8;  // V transpose staging

    const bf16* Kbase = K + (size_t)b * S_LEN * DMODEL + h * HDIM;
    const bf16* Vbase = V + (size_t)b * S_LEN * DMODEL + h * HDIM;

    // Q fragments (B-operand), pre-scaled, held in registers
    const bf16* Qb = Q + (size_t)(b * S_LEN + qt * 64 + wave * 16 + l) * DMODEL + h * HDIM;
    const bf16x8 qf0 = *(const bf16x8*)(Qb + quad * 8);
    const bf16x8 qf1 = *(const bf16x8*)(Qb + 32 + quad * 8);

    float m_run = NEG_INF, l_run = 0.0f;
    f32x4 acc[4] = {};

    // ---- prefetch tile 0 into registers, write buf 0 ----
    bf16x8 kp0, kp1, vp0, vp1;
    int mv = 1;
    {
        const bf16* kg = Kbase + (size_t)kr * DMODEL + ks;
        kp0 = *(const bf16x8*)kg;
        kp1 = *(const bf16x8*)(kg + 8);
        const bf16* vg = Vbase + (size_t)vk0 * DMODEL + vds;
        vp0 = *(const bf16x8*)vg;
        vp1 = *(const bf16x8*)(vg + DMODEL);
        if (wave == 0) mv = amask[b * S_LEN + lane];
    }
    {
        *(bf16x8*)&Ks[0][kr][ks]     = kp0;
        *(bf16x8*)&Ks[0][kr][ks + 8] = kp1;
#pragma unroll
        for (int i = 0; i < 8; ++i) {
            U2 w; w.h[0] = vp0[i]; w.h[1] = vp1[i];
            *(unsigned*)&Vt[0][vds + i][vk0] = w.u;
        }
        if (wave == 0) {
            mk[0][lane] = mv ? 0.0f : NEG_INF;
            unsigned long long bal = __ballot(mv != 0);
            if (lane == 0) flagv[0] = (bal == ~0ULL);
        }
    }
    __syncthreads();
    int buf = 0;

    for (int kt = 0; kt <= qt; ++kt) {
        const bool more = (kt < qt);
        if (more) {   // issue next tile's global loads (consumed after compute)
            const bf16* kg = Kbase + (size_t)((kt + 1) * 64 + kr) * DMODEL + ks;
            kp0 = *(const bf16x8*)kg;
            kp1 = *(const bf16x8*)(kg + 8);
            const bf16* vg = Vbase + (size_t)((kt + 1) * 64 + vk0) * DMODEL + vds;
            vp0 = *(const bf16x8*)vg;
            vp1 = *(const bf16x8*)(vg + DMODEL);
            if (wave == 0) mv = amask[b * S_LEN + (kt + 1) * 64 + lane];
        }

        // ---- compute on buf ----
        const int allv = flagv[buf];
        f32x4 sreg[4] = {};
#pragma unroll
        for (int mi = 0; mi < 4; ++mi) {
            bf16x8 kf0 = *(const bf16x8*)&Ks[buf][mi * 16 + l][quad * 8];
            bf16x8 kf1 = *(const bf16x8*)&Ks[buf][mi * 16 + l][32 + quad * 8];
            sreg[mi] = __builtin_amdgcn_mfma_f32_16x16x32_bf16(kf0, qf0, sreg[mi], 0, 0, 0);
            sreg[mi] = __builtin_amdgcn_mfma_f32_16x16x32_bf16(kf1, qf1, sreg[mi], 0, 0, 0);
        }
        if (!allv) {
#pragma unroll
            for (int mi = 0; mi < 4; ++mi) {
                F4 m4; m4.v = *(const float4*)&mk[buf][mi * 16 + quad * 4];
#pragma unroll
                for (int r = 0; r < 4; ++r) sreg[mi][r] += m4.f[r];
            }
        }
        if (kt == qt) {   // diagonal tile: causal mask
#pragma unroll
            for (int mi = 0; mi < 4; ++mi)
#pragma unroll
                for (int r = 0; r < 4; ++r)
                    if (mi * 16 + quad * 4 + r > wave * 16 + l)
                        sreg[mi][r] = NEG_INF;
        }

        // online softmax (per-lane: one query's 16 keys; 2 shfl levels)
        float mloc = sreg[0][0];
#pragma unroll
        for (int mi = 0; mi < 4; ++mi)
#pragma unroll
            for (int r = 0; r < 4; ++r) mloc = fmaxf(mloc, sreg[mi][r]);
        mloc = fmaxf(mloc, __shfl_xor(mloc, 16, 64));
        mloc = fmaxf(mloc, __shfl_xor(mloc, 32, 64));
        const float mn = fmaxf(m_run, mloc);
        const float alpha = __builtin_amdgcn_exp2f(m_run - mn);
        m_run = mn;
        float ls = 0.0f;
#pragma unroll
        for (int mi = 0; mi < 4; ++mi)
#pragma unroll
            for (int r = 0; r < 4; ++r) {
                const float p = __builtin_amdgcn_exp2f(sreg[mi][r] - mn);
                sreg[mi][r] = p;
                ls += p;
            }
        ls += __shfl_xor(ls, 16, 64);
        ls += __shfl_xor(ls, 32, 64);
        l_run = l_run * alpha + ls;
#pragma unroll
        for (int mi = 0; mi < 4; ++mi)
#pragma unroll
            for (int r = 0; r < 4; ++r) acc[mi][r] *= alpha;

        // pack P^T to bf16 dwords, assemble B-frags via quad-level shfl
        unsigned pk[4][2];
#pragma unroll
        for (int mi = 0; mi < 4; ++mi) {
            U2 w0; w0.h[0] = (bf16)sreg[mi][0]; w0.h[1] = (bf16)sreg[mi][1];
            U2 w1; w1.h[0] = (bf16)sreg[mi][2]; w1.h[1] = (bf16)sreg[mi][3];
            pk[mi][0] = w0.u; pk[mi][1] = w1.u;
        }
        bf16x8 pfrag[2];
#pragma unroll
        for (int kc = 0; kc < 2; ++kc) {
            U8 u;
#pragma unroll
            for (int t = 0; t < 2; ++t) {
                const unsigned a0 = (unsigned)__shfl((int)pk[2 * kc][t],     srcA, 64);
                const unsigned b0 = (unsigned)__shfl((int)pk[2 * kc + 1][t], srcA, 64);
                u.u[t] = qh ? b0 : a0;
                const unsigned a1 = (unsigned)__shfl((int)pk[2 * kc][t],     srcB, 64);
                const unsigned b1 = (unsigned)__shfl((int)pk[2 * kc + 1][t], srcB, 64);
                u.u[2 + t] = qh ? b1 : a1;
            }
            pfrag[kc] = u.v;
        }
        // O^T += V^T · P^T
#pragma unroll
        for (int mi = 0; mi < 4; ++mi) {
            bf16x8 vf0 = *(const bf16x8*)&Vt[buf][mi * 16 + l][quad * 8];
            bf16x8 vf1 = *(const bf16x8*)&Vt[buf][mi * 16 + l][32 + quad * 8];
            acc[mi] = __builtin_amdgcn_mfma_f32_16x16x32_bf16(vf0, pfrag[0], acc[mi], 0, 0, 0);
            acc[mi] = __builtin_amdgcn_mfma_f32_16x16x32_bf16(vf1, pfrag[1], acc[mi], 0, 0, 0);
        }

        // ---- write prefetched tile into the other buffer ----
        if (more) {
            const int nb = buf ^ 1;
            *(bf16x8*)&Ks[nb][kr][ks]     = kp0;
            *(bf16x8*)&Ks[nb][kr][ks + 8] = kp1;
#pragma unroll
            for (int i = 0; i < 8; ++i) {
                U2 w; w.h[0] = vp0[i]; w.h[1] = vp1[i];
                *(unsigned*)&Vt[nb][vds + i][vk0] = w.u;
            }
            if (wave == 0) {
                mk[nb][lane] = mv ? 0.0f : NEG_INF;
                unsigned long long bal = __ballot(mv != 0);
                if (lane == 0) flagv[nb] = (bal == ~0ULL);
            }
        }
        __syncthreads();
        buf ^= 1;
    }

    // epilogue: lane owns query q = wave*16+l, d = mi*16+quad*4+r
    const float rinv = 1.0f / l_run;
#pragma unroll
    for (int mi = 0; mi < 4; ++mi) {
        U2 w0; w0.h[0] = (bf16)(acc[mi][0] * rinv); w0.h[1] = (bf16)(acc[mi][1] * rinv);
        U2 w1; w1.h[0] = (bf16)(acc[mi][2] * rinv); w1.h[1] = (bf16)(acc[mi][3] * rinv);
        *(unsigned*)&Os[wave * 16 + l][mi * 16 + quad * 4]     = w0.u;
        *(unsigned*)&Os[wave * 16 + l][mi * 16 + quad * 4 + 2] = w1.u;
    }
    __syncthreads();
    {   // coalesced store
        const int orow = tid >> 2, oseg = (tid & 3) * 16;
        bf16* Og = O + (size_t)(b * S_LEN + qt * 64 + orow) * DMODEL + h * HDIM + oseg;
        *(bf16x8*)Og       = *(const bf16x8*)&Os[orow][oseg];
        *(bf16x8*)(Og + 8) = *(const bf16x8*)&Os[orow][oseg + 8];
    }
}

// ---------------- launcher ----------------
extern "C" void kernel_launch(void* const* d_in, const int* in_sizes, int n_in,
                              void* d_out, int out_size, void* d_ws, size_t ws_size,
                              hipStream_t stream) {
    const float* x     = (const float*)d_in[0];
    const int*   amask = (const int*)  d_in[1];
    const float* ln1_g = (const float*)d_in[2];
    const float* ln1_b = (const float*)d_in[3];
    const float* ln2_g = (const float*)d_in[4];
    const float* ln2_b = (const float*)d_in[5];
    const float* Wq = (const float*)d_in[6];  const float* bq = (const float*)d_in[7];
    const float* Wk = (const float*)d_in[8];  const float* bk = (const float*)d_in[9];
    const float* Wv = (const float*)d_in[10]; const float* bv = (const float*)d_in[11];
    const float* Wo = (const float*)d_in[12]; const float* bo = (const float*)d_in[13];
    const float* W1 = (const float*)d_in[14]; const float* b1 = (const float*)d_in[15];
    const float* W2 = (const float*)d_in[16]; const float* b2 = (const float*)d_in[17];
    float* out = (float*)d_out;

    char* ws = (char*)d_ws;
    const size_t WSML = (size_t)DMODEL * DMODEL * 2;
    const size_t WBIG = (size_t)DMODEL * DFF_ * 2;
    bf16* Wqt = (bf16*)(ws + 0 * WSML);
    bf16* Wkt = (bf16*)(ws + 1 * WSML);
    bf16* Wvt = (bf16*)(ws + 2 * WSML);
    bf16* Wot = (bf16*)(ws + 3 * WSML);
    bf16* W1t = (bf16*)(ws + 4 * WSML);
    bf16* W2t = (bf16*)(ws + 4 * WSML + WBIG);
    char* act = ws + 4 * WSML + 2 * WBIG;

    const size_t HB = (size_t)MROWS * DMODEL * 2;   // bf16 activation
    const size_t FB = (size_t)MROWS * DMODEL * 4;   // fp32 activation
    bf16*  h    = (bf16*)(act);            // LN1 out; later ctx; later h2
    bf16*  qb   = (bf16*)(act + HB);
    bf16*  kb   = (bf16*)(act + 2 * HB);
    bf16*  vb   = (bf16*)(act + 3 * HB);
    bf16*  ctx  = h;
    float* x1   = (float*)(act + 4 * HB);
    bf16*  f    = (bf16*)(act + 4 * HB + FB);
    bf16*  h2   = h;

    const float SCL = 0.125f * 1.44269504089f;  // 1/sqrt(64) * log2(e), folded into Q

    // 0. fused weight transpose+convert (one launch, 1728 tiles)
    wtrans_all_kernel<<<1728, 256, 0, stream>>>(Wq, Wk, Wv, Wo, W1, W2,
                                                Wqt, Wkt, Wvt, Wot, W1t, W2t);

    // 1. LN1 -> h (bf16)
    ln_kernel<bf16><<<MROWS, 256, 0, stream>>>(x, ln1_g, ln1_b, h);
    // 2. QKV fused, bf16 out; Q pre-scaled by SCL  (1152 blocks)
    mgemm_kernel<128, false, false, true><<<dim3(DMODEL / 128, MROWS / 128, 3), 256, 0, stream>>>(
        h, Wqt, bq, qb, Wkt, bk, kb, Wvt, bv, vb, nullptr, MROWS, DMODEL, DMODEL,
        SCL, 1.0f, 1.0f);
    // 3. flash attention -> ctx (bf16)  (1536 blocks, heavy-first, 4/CU resident)
    mattn_kernel<<<dim3(64, NHEAD, 2), 256, 0, stream>>>(qb, kb, vb, amask, ctx);
    // 4. out proj + residual(x) -> x1 (fp32)  (MT=64: 768 blocks)
    mgemm_kernel<64, false, true, false><<<dim3(DMODEL / 128, MROWS / 64, 1), 256, 0, stream>>>(
        ctx, Wot, bo, x1, Wot, bo, x1, Wot, bo, x1, x, MROWS, DMODEL, DMODEL,
        1.0f, 1.0f, 1.0f);
    // 5. LN2 -> h2 (bf16)
    ln_kernel<bf16><<<MROWS, 256, 0, stream>>>(x1, ln2_g, ln2_b, h2);
    // 6. FF1 + relu -> f (bf16)  (1536 blocks)
    mgemm_kernel<128, true, false, true><<<dim3(DFF_ / 128, MROWS / 128, 1), 256, 0, stream>>>(
        h2, W1t, b1, f, W1t, b1, f, W1t, b1, f, nullptr, MROWS, DFF_, DMODEL,
        1.0f, 1.0f, 1.0f);
    // 7. FF2 + residual(x1) -> out (fp32)  (MT=64: 768 blocks)
    mgemm_kernel<64, false, true, false><<<dim3(DMODEL / 128, MROWS / 64, 1), 256, 0, stream>>>(
        f, W2t, b2, out, W2t, b2, out, W2t, b2, out, x1, MROWS, DMODEL, DFF_,
        1.0f, 1.0f, 1.0f);
}

// Round 10
// 493.773 us; speedup vs baseline: 1.4397x; 1.1580x over previous
//
#include <hip/hip_runtime.h>
#include <hip/hip_bf16.h>
#include <math.h>

#define S_LEN 4096
#define DMODEL 768
#define NHEAD 12
#define HDIM 64
#define DFF_ 3072
#define MROWS 8192  // B*S

typedef __bf16 bf16;
typedef __bf16 bf16x4 __attribute__((ext_vector_type(4)));
typedef __bf16 bf16x8 __attribute__((ext_vector_type(8)));
typedef float f32x4 __attribute__((ext_vector_type(4)));

union F4 { float4 v; float f[4]; };
union U2 { bf16 h[2]; unsigned u; };
union U8 { unsigned u[4]; bf16x8 v; };

__device__ __forceinline__ void gld_lds16(void* lds, const void* g) {
    __builtin_amdgcn_global_load_lds(
        (const __attribute__((address_space(1))) unsigned int*)g,
        (__attribute__((address_space(3))) unsigned int*)lds, 16, 0, 0);
}

// ---------------- LayerNorm ----------------
template<typename OUT>
__global__ __launch_bounds__(256) void ln_kernel(const float* __restrict__ x,
                                                 const float* __restrict__ g,
                                                 const float* __restrict__ bta,
                                                 OUT* __restrict__ out) {
    const int row = blockIdx.x;
    const int t = threadIdx.x;
    const float* xr = x + (size_t)row * DMODEL;
    float v0 = xr[t], v1 = xr[t + 256], v2 = xr[t + 512];
    float s = v0 + v1 + v2;
    float ss = v0 * v0 + v1 * v1 + v2 * v2;
    for (int o = 32; o > 0; o >>= 1) {
        s += __shfl_down(s, o, 64);
        ss += __shfl_down(ss, o, 64);
    }
    __shared__ float sm[4], sm2[4];
    const int w = t >> 6, lane = t & 63;
    if (lane == 0) { sm[w] = s; sm2[w] = ss; }
    __syncthreads();
    s = sm[0] + sm[1] + sm[2] + sm[3];
    ss = sm2[0] + sm2[1] + sm2[2] + sm2[3];
    const float mu = s * (1.0f / DMODEL);
    const float var = ss * (1.0f / DMODEL) - mu * mu;
    const float rs = rsqrtf(var + 1e-5f);
    OUT* orow = out + (size_t)row * DMODEL;
    orow[t]       = (OUT)((v0 - mu) * rs * g[t]       + bta[t]);
    orow[t + 256] = (OUT)((v1 - mu) * rs * g[t + 256] + bta[t + 256]);
    orow[t + 512] = (OUT)((v2 - mu) * rs * g[t + 512] + bta[t + 512]);
}

// ---------------- fused weight transpose+convert: all 6 weights, one launch ----------------
__global__ __launch_bounds__(256) void wtrans_all_kernel(
    const float* __restrict__ Wq, const float* __restrict__ Wk,
    const float* __restrict__ Wv, const float* __restrict__ Wo,
    const float* __restrict__ W1, const float* __restrict__ W2,
    bf16* __restrict__ Wqt, bf16* __restrict__ Wkt, bf16* __restrict__ Wvt,
    bf16* __restrict__ Wot, bf16* __restrict__ W1t, bf16* __restrict__ W2t) {
    int t = blockIdx.x;
    const float* W; bf16* Wt; int K, N;
    if      (t < 144)  { W = Wq; Wt = Wqt; K = 768;  N = 768;  }
    else if (t < 288)  { W = Wk; Wt = Wkt; K = 768;  N = 768;  t -= 144; }
    else if (t < 432)  { W = Wv; Wt = Wvt; K = 768;  N = 768;  t -= 288; }
    else if (t < 576)  { W = Wo; Wt = Wot; K = 768;  N = 768;  t -= 432; }
    else if (t < 1152) { W = W1; Wt = W1t; K = 768;  N = 3072; t -= 576; }
    else               { W = W2; Wt = W2t; K = 3072; N = 768;  t -= 1152; }
    const int nx = N >> 6;
    const int n0 = (t % nx) * 64, k0 = (t / nx) * 64;

    __shared__ float tile[64][65];
    const int tid = threadIdx.x;
    const int lr = tid >> 4, lc = (tid & 15) << 2;
#pragma unroll
    for (int i = 0; i < 4; ++i) {
        const int r = lr + i * 16;
        F4 w; w.v = *(const float4*)&W[(size_t)(k0 + r) * N + n0 + lc];
#pragma unroll
        for (int j = 0; j < 4; ++j) tile[r][lc + j] = w.f[j];
    }
    __syncthreads();
#pragma unroll
    for (int i = 0; i < 4; ++i) {
        const int n = lr + i * 16;
        bf16x4 o;
#pragma unroll
        for (int j = 0; j < 4; ++j) o[j] = (bf16)tile[lc + j][n];
        *(bf16x4*)&Wt[(size_t)(n0 + n) * K + k0 + lc] = o;
    }
}

// ---------------- bf16 MFMA GEMM (m97 structure), MT x 128 tile, K-offset ----------------
// K = leading dim (stride); Kloop = K-extent of this block's work; koff = start.
template<int MT, bool RELU, bool RES, bool OUT_BF16>
__global__ __launch_bounds__(256) void mgemm_kernel(
    const bf16* __restrict__ A,
    const bf16* __restrict__ Wt0, const float* __restrict__ bias0, void* __restrict__ C0,
    const bf16* __restrict__ Wt1, const float* __restrict__ bias1, void* __restrict__ C1,
    const bf16* __restrict__ Wt2, const float* __restrict__ bias2, void* __restrict__ C2,
    const float* __restrict__ R, int M, int N, int K, int Kloop,
    int koff0, int koff1, int koff2,
    float sc0, float sc1, float sc2) {
    const bf16* Wt = Wt0; const float* bias = bias0; void* C = C0; float sc = sc0; int koff = koff0;
    if (blockIdx.z == 1) { Wt = Wt1; bias = bias1; C = C1; sc = sc1; koff = koff1; }
    if (blockIdx.z == 2) { Wt = Wt2; bias = bias2; C = C2; sc = sc2; koff = koff2; }

    constexpr int NI = (MT == 128) ? 4 : 2;
    __shared__ bf16 As[MT * 32];
    __shared__ bf16 Bs[128 * 32];

    const int tid = threadIdx.x;
    const int wave = tid >> 6, lane = tid & 63;
    const int row0 = blockIdx.y * MT, col0 = blockIdx.x * 128;
    const int wr = (MT == 128) ? (wave >> 1) * 64 : 0;
    const int wc = (MT == 128) ? (wave & 1) * 64 : wave * 32;
    const int mrow = lane & 15, kq = (lane >> 4) * 8;

    const int st_row = (lane >> 2);
    const int st_off = (lane & 3) * 16;

    f32x4 acc[4][NI] = {};

    const char* Ab = (const char*)(A + (size_t)row0 * K + koff);
    const char* Bb = (const char*)(Wt + (size_t)col0 * K + koff);
    const size_t strideA = (size_t)K * 2;

    for (int k0 = 0; k0 < Kloop; k0 += 32) {
        if (MT == 128) {
#pragma unroll
            for (int issue = 0; issue < 2; ++issue) {
                const int r = wave * 32 + issue * 16 + st_row;
                gld_lds16((char*)As + (wave * 32 + issue * 16) * 64,
                          Ab + (size_t)r * strideA + k0 * 2 + st_off);
            }
        } else {
            const int r = wave * 16 + st_row;
            gld_lds16((char*)As + (wave * 16) * 64,
                      Ab + (size_t)r * strideA + k0 * 2 + st_off);
        }
#pragma unroll
        for (int issue = 0; issue < 2; ++issue) {
            const int r = wave * 32 + issue * 16 + st_row;
            gld_lds16((char*)Bs + (wave * 32 + issue * 16) * 64,
                      Bb + (size_t)r * strideA + k0 * 2 + st_off);
        }
        __syncthreads();
        bf16x8 af[4], bfr[NI];
#pragma unroll
        for (int mi = 0; mi < 4; ++mi)
            af[mi] = *(const bf16x8*)&As[(wr + mi * 16 + mrow) * 32 + kq];
#pragma unroll
        for (int ni = 0; ni < NI; ++ni)
            bfr[ni] = *(const bf16x8*)&Bs[(wc + ni * 16 + mrow) * 32 + kq];
#pragma unroll
        for (int mi = 0; mi < 4; ++mi)
#pragma unroll
            for (int ni = 0; ni < NI; ++ni)
                acc[mi][ni] = __builtin_amdgcn_mfma_f32_16x16x32_bf16(
                    af[mi], bfr[ni], acc[mi][ni], 0, 0, 0);
        __syncthreads();
    }

    const int quad = lane >> 4;
    float bv[NI];
#pragma unroll
    for (int ni = 0; ni < NI; ++ni) bv[ni] = bias[col0 + wc + ni * 16 + mrow];
#pragma unroll
    for (int mi = 0; mi < 4; ++mi) {
#pragma unroll
        for (int r = 0; r < 4; ++r) {
            const int row = row0 + wr + mi * 16 + quad * 4 + r;
#pragma unroll
            for (int ni = 0; ni < NI; ++ni) {
                const int col = col0 + wc + ni * 16 + mrow;
                float v = acc[mi][ni][r] + bv[ni];
                if (RES) v += R[(size_t)row * N + col];
                v *= sc;
                if (RELU) v = fmaxf(v, 0.0f);
                if (OUT_BF16) ((bf16*)C)[(size_t)row * N + col] = (bf16)v;
                else          ((float*)C)[(size_t)row * N + col] = v;
            }
        }
    }
}

// ---------------- FF2 split-K combine: out = p0 + p1 + b2 + x1 ----------------
__global__ __launch_bounds__(256) void ff2_combine_kernel(
    const bf16* __restrict__ p0, const bf16* __restrict__ p1,
    const float* __restrict__ b2, const float* __restrict__ x1,
    float* __restrict__ out) {
    const int i = (blockIdx.x * 256 + threadIdx.x) * 4;
    bf16x4 a = *(const bf16x4*)(p0 + i);
    bf16x4 b = *(const bf16x4*)(p1 + i);
    F4 xr; xr.v = *(const float4*)(x1 + i);
    const int col = i % DMODEL;
    F4 o;
#pragma unroll
    for (int j = 0; j < 4; ++j)
        o.f[j] = (float)a[j] + (float)b[j] + b2[col + j] + xr.f[j];
    *(float4*)(out + i) = o.v;
}

// ---------------- Transposed-S MFMA flash attention (R6 config — best measured) ----------------
// S^T = K·Q^T; P^T re-layout via quad-level shfl (no LDS round trip).
// Q pre-scaled by 0.125*log2(e). grid (32,H,B) = 768 paired-uniform blocks
// ({63-bx, bx} -> 65 iters each). Double-buffered K/V, 1 barrier/iter.
__global__ __launch_bounds__(256) void mattn_kernel(
    const bf16* __restrict__ Q, const bf16* __restrict__ K,
    const bf16* __restrict__ V, const int* __restrict__ amask,
    bf16* __restrict__ O) {
    const int bx = blockIdx.x, h = blockIdx.y, b = blockIdx.z;

    __shared__ bf16 Ks[2][64][68];   // [buf][key][d]  (136 B rows: conflict-free)
    __shared__ bf16 Vt[2][64][68];   // [buf][d][key]
    __shared__ bf16 Os[64][68];      // epilogue bounce
    __shared__ float mk[2][64];
    __shared__ int flagv[2];

    const int tid = threadIdx.x;
    const int wave = tid >> 6, lane = tid & 63;
    const int l = lane & 15, quad = lane >> 4;
    const int qh = quad >> 1;
    const int srcA = (quad & 1) * 32 + l;
    const int srcB = srcA + 16;
    const float NEG_INF = -__builtin_huge_valf();

    const int kr = tid >> 2, ks = (tid & 3) * 16;          // K tile staging
    const int vk0 = (tid & 31) * 2, vds = (tid >> 5) * 8;  // V transpose staging

    const bf16* Kbase = K + (size_t)b * S_LEN * DMODEL + h * HDIM;
    const bf16* Vbase = V + (size_t)b * S_LEN * DMODEL + h * HDIM;

#pragma unroll 1
    for (int pass = 0; pass < 2; ++pass) {
        const int qt = pass ? bx : (63 - bx);

        const bf16* Qb = Q + (size_t)(b * S_LEN + qt * 64 + wave * 16 + l) * DMODEL + h * HDIM;
        const bf16x8 qf0 = *(const bf16x8*)(Qb + quad * 8);
        const bf16x8 qf1 = *(const bf16x8*)(Qb + 32 + quad * 8);

        float m_run = NEG_INF, l_run = 0.0f;
        f32x4 acc[4] = {};

        // ---- prefetch tile 0 into registers ----
        bf16x8 kp0, kp1, vp0, vp1;
        int mv = 1;
        {
            const bf16* kg = Kbase + (size_t)kr * DMODEL + ks;
            kp0 = *(const bf16x8*)kg;
            kp1 = *(const bf16x8*)(kg + 8);
            const bf16* vg = Vbase + (size_t)vk0 * DMODEL + vds;
            vp0 = *(const bf16x8*)vg;
            vp1 = *(const bf16x8*)(vg + DMODEL);
            if (wave == 0) mv = amask[b * S_LEN + lane];
        }
        __syncthreads();   // prior pass epilogue LDS reads complete
        {
            *(bf16x8*)&Ks[0][kr][ks]     = kp0;
            *(bf16x8*)&Ks[0][kr][ks + 8] = kp1;
#pragma unroll
            for (int i = 0; i < 8; ++i) {
                U2 w; w.h[0] = vp0[i]; w.h[1] = vp1[i];
                *(unsigned*)&Vt[0][vds + i][vk0] = w.u;
            }
            if (wave == 0) {
                mk[0][lane] = mv ? 0.0f : NEG_INF;
                unsigned long long bal = __ballot(mv != 0);
                if (lane == 0) flagv[0] = (bal == ~0ULL);
            }
        }
        __syncthreads();
        int buf = 0;

        for (int kt = 0; kt <= qt; ++kt) {
            const bool more = (kt < qt);
            if (more) {
                const bf16* kg = Kbase + (size_t)((kt + 1) * 64 + kr) * DMODEL + ks;
                kp0 = *(const bf16x8*)kg;
                kp1 = *(const bf16x8*)(kg + 8);
                const bf16* vg = Vbase + (size_t)((kt + 1) * 64 + vk0) * DMODEL + vds;
                vp0 = *(const bf16x8*)vg;
                vp1 = *(const bf16x8*)(vg + DMODEL);
                if (wave == 0) mv = amask[b * S_LEN + (kt + 1) * 64 + lane];
            }

            const int allv = flagv[buf];
            f32x4 sreg[4] = {};
#pragma unroll
            for (int mi = 0; mi < 4; ++mi) {
                bf16x8 kf0 = *(const bf16x8*)&Ks[buf][mi * 16 + l][quad * 8];
                bf16x8 kf1 = *(const bf16x8*)&Ks[buf][mi * 16 + l][32 + quad * 8];
                sreg[mi] = __builtin_amdgcn_mfma_f32_16x16x32_bf16(kf0, qf0, sreg[mi], 0, 0, 0);
                sreg[mi] = __builtin_amdgcn_mfma_f32_16x16x32_bf16(kf1, qf1, sreg[mi], 0, 0, 0);
            }
            if (!allv) {
#pragma unroll
                for (int mi = 0; mi < 4; ++mi) {
                    F4 m4; m4.v = *(const float4*)&mk[buf][mi * 16 + quad * 4];
#pragma unroll
                    for (int r = 0; r < 4; ++r) sreg[mi][r] += m4.f[r];
                }
            }
            if (kt == qt) {
#pragma unroll
                for (int mi = 0; mi < 4; ++mi)
#pragma unroll
                    for (int r = 0; r < 4; ++r)
                        if (mi * 16 + quad * 4 + r > wave * 16 + l)
                            sreg[mi][r] = NEG_INF;
            }

            float mloc = sreg[0][0];
#pragma unroll
            for (int mi = 0; mi < 4; ++mi)
#pragma unroll
                for (int r = 0; r < 4; ++r) mloc = fmaxf(mloc, sreg[mi][r]);
            mloc = fmaxf(mloc, __shfl_xor(mloc, 16, 64));
            mloc = fmaxf(mloc, __shfl_xor(mloc, 32, 64));
            const float mn = fmaxf(m_run, mloc);
            const float alpha = __builtin_amdgcn_exp2f(m_run - mn);
            m_run = mn;
            float ls = 0.0f;
#pragma unroll
            for (int mi = 0; mi < 4; ++mi)
#pragma unroll
                for (int r = 0; r < 4; ++r) {
                    const float p = __builtin_amdgcn_exp2f(sreg[mi][r] - mn);
                    sreg[mi][r] = p;
                    ls += p;
                }
            ls += __shfl_xor(ls, 16, 64);
            ls += __shfl_xor(ls, 32, 64);
            l_run = l_run * alpha + ls;
#pragma unroll
            for (int mi = 0; mi < 4; ++mi)
#pragma unroll
                for (int r = 0; r < 4; ++r) acc[mi][r] *= alpha;

            unsigned pk[4][2];
#pragma unroll
            for (int mi = 0; mi < 4; ++mi) {
                U2 w0; w0.h[0] = (bf16)sreg[mi][0]; w0.h[1] = (bf16)sreg[mi][1];
                U2 w1; w1.h[0] = (bf16)sreg[mi][2]; w1.h[1] = (bf16)sreg[mi][3];
                pk[mi][0] = w0.u; pk[mi][1] = w1.u;
            }
            bf16x8 pfrag[2];
#pragma unroll
            for (int kc = 0; kc < 2; ++kc) {
                U8 u;
#pragma unroll
                for (int t = 0; t < 2; ++t) {
                    const unsigned a0 = (unsigned)__shfl((int)pk[2 * kc][t],     srcA, 64);
                    const unsigned b0 = (unsigned)__shfl((int)pk[2 * kc + 1][t], srcA, 64);
                    u.u[t] = qh ? b0 : a0;
                    const unsigned a1 = (unsigned)__shfl((int)pk[2 * kc][t],     srcB, 64);
                    const unsigned b1 = (unsigned)__shfl((int)pk[2 * kc + 1][t], srcB, 64);
                    u.u[2 + t] = qh ? b1 : a1;
                }
                pfrag[kc] = u.v;
            }
#pragma unroll
            for (int mi = 0; mi < 4; ++mi) {
                bf16x8 vf0 = *(const bf16x8*)&Vt[buf][mi * 16 + l][quad * 8];
                bf16x8 vf1 = *(const bf16x8*)&Vt[buf][mi * 16 + l][32 + quad * 8];
                acc[mi] = __builtin_amdgcn_mfma_f32_16x16x32_bf16(vf0, pfrag[0], acc[mi], 0, 0, 0);
                acc[mi] = __builtin_amdgcn_mfma_f32_16x16x32_bf16(vf1, pfrag[1], acc[mi], 0, 0, 0);
            }

            if (more) {
                const int nb = buf ^ 1;
                *(bf16x8*)&Ks[nb][kr][ks]     = kp0;
                *(bf16x8*)&Ks[nb][kr][ks + 8] = kp1;
#pragma unroll
                for (int i = 0; i < 8; ++i) {
                    U2 w; w.h[0] = vp0[i]; w.h[1] = vp1[i];
                    *(unsigned*)&Vt[nb][vds + i][vk0] = w.u;
                }
                if (wave == 0) {
                    mk[nb][lane] = mv ? 0.0f : NEG_INF;
                    unsigned long long bal = __ballot(mv != 0);
                    if (lane == 0) flagv[nb] = (bal == ~0ULL);
                }
            }
            __syncthreads();
            buf ^= 1;
        }

        const float rinv = 1.0f / l_run;
#pragma unroll
        for (int mi = 0; mi < 4; ++mi) {
            U2 w0; w0.h[0] = (bf16)(acc[mi][0] * rinv); w0.h[1] = (bf16)(acc[mi][1] * rinv);
            U2 w1; w1.h[0] = (bf16)(acc[mi][2] * rinv); w1.h[1] = (bf16)(acc[mi][3] * rinv);
            *(unsigned*)&Os[wave * 16 + l][mi * 16 + quad * 4]     = w0.u;
            *(unsigned*)&Os[wave * 16 + l][mi * 16 + quad * 4 + 2] = w1.u;
        }
        __syncthreads();
        {
            const int orow = tid >> 2, oseg = (tid & 3) * 16;
            bf16* Og = O + (size_t)(b * S_LEN + qt * 64 + orow) * DMODEL + h * HDIM + oseg;
            *(bf16x8*)Og       = *(const bf16x8*)&Os[orow][oseg];
            *(bf16x8*)(Og + 8) = *(const bf16x8*)&Os[orow][oseg + 8];
        }
    }
}

// ---------------- launcher ----------------
extern "C" void kernel_launch(void* const* d_in, const int* in_sizes, int n_in,
                              void* d_out, int out_size, void* d_ws, size_t ws_size,
                              hipStream_t stream) {
    const float* x     = (const float*)d_in[0];
    const int*   amask = (const int*)  d_in[1];
    const float* ln1_g = (const float*)d_in[2];
    const float* ln1_b = (const float*)d_in[3];
    const float* ln2_g = (const float*)d_in[4];
    const float* ln2_b = (const float*)d_in[5];
    const float* Wq = (const float*)d_in[6];  const float* bq = (const float*)d_in[7];
    const float* Wk = (const float*)d_in[8];  const float* bk = (const float*)d_in[9];
    const float* Wv = (const float*)d_in[10]; const float* bv = (const float*)d_in[11];
    const float* Wo = (const float*)d_in[12]; const float* bo = (const float*)d_in[13];
    const float* W1 = (const float*)d_in[14]; const float* b1 = (const float*)d_in[15];
    const float* W2 = (const float*)d_in[16]; const float* b2 = (const float*)d_in[17];
    float* out = (float*)d_out;

    char* ws = (char*)d_ws;
    const size_t WSML = (size_t)DMODEL * DMODEL * 2;
    const size_t WBIG = (size_t)DMODEL * DFF_ * 2;
    bf16* Wqt = (bf16*)(ws + 0 * WSML);
    bf16* Wkt = (bf16*)(ws + 1 * WSML);
    bf16* Wvt = (bf16*)(ws + 2 * WSML);
    bf16* Wot = (bf16*)(ws + 3 * WSML);
    bf16* W1t = (bf16*)(ws + 4 * WSML);
    bf16* W2t = (bf16*)(ws + 4 * WSML + WBIG);
    char* act = ws + 4 * WSML + 2 * WBIG;

    const size_t HB = (size_t)MROWS * DMODEL * 2;   // bf16 activation (12.6 MB)
    const size_t FB = (size_t)MROWS * DMODEL * 4;   // fp32 activation (25.2 MB)
    bf16*  h    = (bf16*)(act);            // LN1 out; later ctx; later h2
    bf16*  qb   = (bf16*)(act + HB);
    bf16*  kb   = (bf16*)(act + 2 * HB);
    bf16*  vb   = (bf16*)(act + 3 * HB);
    bf16*  ctx  = h;
    float* x1   = (float*)(act + 4 * HB);
    bf16*  f    = (bf16*)(act + 4 * HB + FB);      // FF1 out: 8192x3072 bf16 (50.3 MB)
    bf16*  h2   = h;
    // FF2 split-K partials reuse dead q/k buffers; zero-bias buffer in dead vb.
    bf16*  p0   = qb;
    bf16*  p1   = kb;
    float* zbias = (float*)vb;

    const float SCL = 0.125f * 1.44269504089f;  // 1/sqrt(64) * log2(e), folded into Q

    // 0. fused weight transpose+convert (one launch, 1728 tiles)
    wtrans_all_kernel<<<1728, 256, 0, stream>>>(Wq, Wk, Wv, Wo, W1, W2,
                                                Wqt, Wkt, Wvt, Wot, W1t, W2t);

    // 1. LN1 -> h (bf16)
    ln_kernel<bf16><<<MROWS, 256, 0, stream>>>(x, ln1_g, ln1_b, h);
    // 2. QKV fused, bf16 out; Q pre-scaled by SCL  (1152 blocks)
    mgemm_kernel<128, false, false, true><<<dim3(DMODEL / 128, MROWS / 128, 3), 256, 0, stream>>>(
        h, Wqt, bq, qb, Wkt, bk, kb, Wvt, bv, vb, nullptr,
        MROWS, DMODEL, DMODEL, DMODEL, 0, 0, 0, SCL, 1.0f, 1.0f);
    // 3. flash attention -> ctx (bf16)  (768 paired-uniform blocks — best measured)
    mattn_kernel<<<dim3(32, NHEAD, 2), 256, 0, stream>>>(qb, kb, vb, amask, ctx);
    // zero the 768-float bias buffer for split-K partials (vb is dead now)
    hipMemsetAsync(zbias, 0, DMODEL * sizeof(float), stream);
    // 4. out proj + residual(x) -> x1 (fp32)  (MT=64: 768 blocks)
    mgemm_kernel<64, false, true, false><<<dim3(DMODEL / 128, MROWS / 64, 1), 256, 0, stream>>>(
        ctx, Wot, bo, x1, Wot, bo, x1, Wot, bo, x1, x,
        MROWS, DMODEL, DMODEL, DMODEL, 0, 0, 0, 1.0f, 1.0f, 1.0f);
    // 5. LN2 -> h2 (bf16)
    ln_kernel<bf16><<<MROWS, 256, 0, stream>>>(x1, ln2_g, ln2_b, h2);
    // 6. FF1 + relu -> f (bf16)  (1536 blocks)
    mgemm_kernel<128, true, false, true><<<dim3(DFF_ / 128, MROWS / 128, 1), 256, 0, stream>>>(
        h2, W1t, b1, f, W1t, b1, f, W1t, b1, f, nullptr,
        MROWS, DFF_, DMODEL, DMODEL, 0, 0, 0, 1.0f, 1.0f, 1.0f);
    // 7. FF2 split-K: z=0 -> K[0,1536) into p0; z=1 -> K[1536,3072) into p1
    //    (768 blocks total, MT=128 full 16-MFMA density, 48 iters each)
    mgemm_kernel<128, false, false, true><<<dim3(DMODEL / 128, MROWS / 128, 2), 256, 0, stream>>>(
        f, W2t, zbias, p0, W2t, zbias, p1, W2t, zbias, p1, nullptr,
        MROWS, DMODEL, DFF_, DFF_ / 2, 0, DFF_ / 2, 0, 1.0f, 1.0f, 1.0f);
    // 7b. combine: out = p0 + p1 + b2 + x1  (6144 blocks, ~100 MB traffic)
    ff2_combine_kernel<<<(MROWS * DMODEL) / 1024, 256, 0, stream>>>(p0, p1, b2, x1, out);
}

// Round 11
// 469.908 us; speedup vs baseline: 1.5128x; 1.0508x over previous
//
#include <hip/hip_runtime.h>
#include <hip/hip_bf16.h>
#include <math.h>

#define S_LEN 4096
#define DMODEL 768
#define NHEAD 12
#define HDIM 64
#define DFF_ 3072
#define MROWS 8192  // B*S

typedef __bf16 bf16;
typedef __bf16 bf16x4 __attribute__((ext_vector_type(4)));
typedef __bf16 bf16x8 __attribute__((ext_vector_type(8)));
typedef float f32x4 __attribute__((ext_vector_type(4)));
typedef short s16x4 __attribute__((ext_vector_type(4)));

union F4 { float4 v; float f[4]; };
union U2 { bf16 h[2]; unsigned u; };
union U8 { unsigned u[4]; bf16x8 v; };

// 16x16x16 bf16 MFMA: B-operand layout B[k=quad*4+j][n=l] == S^T C-layout,
// so softmax'd P feeds PV directly with ZERO cross-lane movement.
#if __has_builtin(__builtin_amdgcn_mfma_f32_16x16x16bf16_1k)
typedef s16x4 mf16_t;
#define MFMA16(a, b, c) __builtin_amdgcn_mfma_f32_16x16x16bf16_1k((a), (b), (c), 0, 0, 0)
#define HAVE_MFMA16 1
#elif __has_builtin(__builtin_amdgcn_mfma_f32_16x16x16_bf16)
typedef bf16x4 mf16_t;
#define MFMA16(a, b, c) __builtin_amdgcn_mfma_f32_16x16x16_bf16((a), (b), (c), 0, 0, 0)
#define HAVE_MFMA16 1
#else
#define HAVE_MFMA16 0
#endif

#if HAVE_MFMA16
union U4 { unsigned u[2]; mf16_t v; };
#endif

__device__ __forceinline__ void gld_lds16(void* lds, const void* g) {
    __builtin_amdgcn_global_load_lds(
        (const __attribute__((address_space(1))) unsigned int*)g,
        (__attribute__((address_space(3))) unsigned int*)lds, 16, 0, 0);
}

// ---------------- LayerNorm ----------------
template<typename OUT>
__global__ __launch_bounds__(256) void ln_kernel(const float* __restrict__ x,
                                                 const float* __restrict__ g,
                                                 const float* __restrict__ bta,
                                                 OUT* __restrict__ out) {
    const int row = blockIdx.x;
    const int t = threadIdx.x;
    const float* xr = x + (size_t)row * DMODEL;
    float v0 = xr[t], v1 = xr[t + 256], v2 = xr[t + 512];
    float s = v0 + v1 + v2;
    float ss = v0 * v0 + v1 * v1 + v2 * v2;
    for (int o = 32; o > 0; o >>= 1) {
        s += __shfl_down(s, o, 64);
        ss += __shfl_down(ss, o, 64);
    }
    __shared__ float sm[4], sm2[4];
    const int w = t >> 6, lane = t & 63;
    if (lane == 0) { sm[w] = s; sm2[w] = ss; }
    __syncthreads();
    s = sm[0] + sm[1] + sm[2] + sm[3];
    ss = sm2[0] + sm2[1] + sm2[2] + sm2[3];
    const float mu = s * (1.0f / DMODEL);
    const float var = ss * (1.0f / DMODEL) - mu * mu;
    const float rs = rsqrtf(var + 1e-5f);
    OUT* orow = out + (size_t)row * DMODEL;
    orow[t]       = (OUT)((v0 - mu) * rs * g[t]       + bta[t]);
    orow[t + 256] = (OUT)((v1 - mu) * rs * g[t + 256] + bta[t + 256]);
    orow[t + 512] = (OUT)((v2 - mu) * rs * g[t + 512] + bta[t + 512]);
}

// ---------------- fused weight transpose+convert: all 6 weights, one launch ----------------
__global__ __launch_bounds__(256) void wtrans_all_kernel(
    const float* __restrict__ Wq, const float* __restrict__ Wk,
    const float* __restrict__ Wv, const float* __restrict__ Wo,
    const float* __restrict__ W1, const float* __restrict__ W2,
    bf16* __restrict__ Wqt, bf16* __restrict__ Wkt, bf16* __restrict__ Wvt,
    bf16* __restrict__ Wot, bf16* __restrict__ W1t, bf16* __restrict__ W2t) {
    int t = blockIdx.x;
    const float* W; bf16* Wt; int K, N;
    if      (t < 144)  { W = Wq; Wt = Wqt; K = 768;  N = 768;  }
    else if (t < 288)  { W = Wk; Wt = Wkt; K = 768;  N = 768;  t -= 144; }
    else if (t < 432)  { W = Wv; Wt = Wvt; K = 768;  N = 768;  t -= 288; }
    else if (t < 576)  { W = Wo; Wt = Wot; K = 768;  N = 768;  t -= 432; }
    else if (t < 1152) { W = W1; Wt = W1t; K = 768;  N = 3072; t -= 576; }
    else               { W = W2; Wt = W2t; K = 3072; N = 768;  t -= 1152; }
    const int nx = N >> 6;
    const int n0 = (t % nx) * 64, k0 = (t / nx) * 64;

    __shared__ float tile[64][65];
    const int tid = threadIdx.x;
    const int lr = tid >> 4, lc = (tid & 15) << 2;
#pragma unroll
    for (int i = 0; i < 4; ++i) {
        const int r = lr + i * 16;
        F4 w; w.v = *(const float4*)&W[(size_t)(k0 + r) * N + n0 + lc];
#pragma unroll
        for (int j = 0; j < 4; ++j) tile[r][lc + j] = w.f[j];
    }
    __syncthreads();
#pragma unroll
    for (int i = 0; i < 4; ++i) {
        const int n = lr + i * 16;
        bf16x4 o;
#pragma unroll
        for (int j = 0; j < 4; ++j) o[j] = (bf16)tile[lc + j][n];
        *(bf16x4*)&Wt[(size_t)(n0 + n) * K + k0 + lc] = o;
    }
}

// ---------------- bf16 MFMA GEMM, MT x 128 tile, BK=64 (2 sub-tiles / barrier) ----------------
// Two BK=32 sub-tiles staged into separate 64B-row LDS buffers before ONE
// barrier pair -> barrier count halves vs BK=32 (short-K loops are drain-bound).
template<int MT, bool RELU, bool RES, bool OUT_BF16>
__global__ __launch_bounds__(256) void mgemm_kernel(
    const bf16* __restrict__ A,
    const bf16* __restrict__ Wt0, const float* __restrict__ bias0, void* __restrict__ C0,
    const bf16* __restrict__ Wt1, const float* __restrict__ bias1, void* __restrict__ C1,
    const bf16* __restrict__ Wt2, const float* __restrict__ bias2, void* __restrict__ C2,
    const float* __restrict__ R, int M, int N, int K, int Kloop,
    int koff0, int koff1, int koff2,
    float sc0, float sc1, float sc2) {
    const bf16* Wt = Wt0; const float* bias = bias0; void* C = C0; float sc = sc0; int koff = koff0;
    if (blockIdx.z == 1) { Wt = Wt1; bias = bias1; C = C1; sc = sc1; koff = koff1; }
    if (blockIdx.z == 2) { Wt = Wt2; bias = bias2; C = C2; sc = sc2; koff = koff2; }

    constexpr int NI = (MT == 128) ? 4 : 2;
    __shared__ bf16 As[2][MT * 32];
    __shared__ bf16 Bs[2][128 * 32];

    const int tid = threadIdx.x;
    const int wave = tid >> 6, lane = tid & 63;
    const int row0 = blockIdx.y * MT, col0 = blockIdx.x * 128;
    const int wr = (MT == 128) ? (wave >> 1) * 64 : 0;
    const int wc = (MT == 128) ? (wave & 1) * 64 : wave * 32;
    const int mrow = lane & 15, kq = (lane >> 4) * 8;

    const int st_row = (lane >> 2);
    const int st_off = (lane & 3) * 16;

    f32x4 acc[4][NI] = {};

    const char* Ab = (const char*)(A + (size_t)row0 * K + koff);
    const char* Bb = (const char*)(Wt + (size_t)col0 * K + koff);
    const size_t strideA = (size_t)K * 2;

    for (int k0 = 0; k0 < Kloop; k0 += 64) {
#pragma unroll
        for (int s = 0; s < 2; ++s) {
            const int kk = k0 + s * 32;
            if (MT == 128) {
#pragma unroll
                for (int issue = 0; issue < 2; ++issue) {
                    const int r = wave * 32 + issue * 16 + st_row;
                    gld_lds16((char*)As[s] + (wave * 32 + issue * 16) * 64,
                              Ab + (size_t)r * strideA + kk * 2 + st_off);
                }
            } else {
                const int r = wave * 16 + st_row;
                gld_lds16((char*)As[s] + (wave * 16) * 64,
                          Ab + (size_t)r * strideA + kk * 2 + st_off);
            }
#pragma unroll
            for (int issue = 0; issue < 2; ++issue) {
                const int r = wave * 32 + issue * 16 + st_row;
                gld_lds16((char*)Bs[s] + (wave * 32 + issue * 16) * 64,
                          Bb + (size_t)r * strideA + kk * 2 + st_off);
            }
        }
        __syncthreads();
#pragma unroll
        for (int s = 0; s < 2; ++s) {
            bf16x8 af[4], bfr[NI];
#pragma unroll
            for (int mi = 0; mi < 4; ++mi)
                af[mi] = *(const bf16x8*)&As[s][(wr + mi * 16 + mrow) * 32 + kq];
#pragma unroll
            for (int ni = 0; ni < NI; ++ni)
                bfr[ni] = *(const bf16x8*)&Bs[s][(wc + ni * 16 + mrow) * 32 + kq];
#pragma unroll
            for (int mi = 0; mi < 4; ++mi)
#pragma unroll
                for (int ni = 0; ni < NI; ++ni)
                    acc[mi][ni] = __builtin_amdgcn_mfma_f32_16x16x32_bf16(
                        af[mi], bfr[ni], acc[mi][ni], 0, 0, 0);
        }
        __syncthreads();
    }

    const int quad = lane >> 4;
    float bv[NI];
#pragma unroll
    for (int ni = 0; ni < NI; ++ni) bv[ni] = bias[col0 + wc + ni * 16 + mrow];
#pragma unroll
    for (int mi = 0; mi < 4; ++mi) {
#pragma unroll
        for (int r = 0; r < 4; ++r) {
            const int row = row0 + wr + mi * 16 + quad * 4 + r;
#pragma unroll
            for (int ni = 0; ni < NI; ++ni) {
                const int col = col0 + wc + ni * 16 + mrow;
                float v = acc[mi][ni][r] + bv[ni];
                if (RES) v += R[(size_t)row * N + col];
                v *= sc;
                if (RELU) v = fmaxf(v, 0.0f);
                if (OUT_BF16) ((bf16*)C)[(size_t)row * N + col] = (bf16)v;
                else          ((float*)C)[(size_t)row * N + col] = v;
            }
        }
    }
}

// ---------------- FF2 split-K combine: out = p0 + p1 + b2 + x1 ----------------
__global__ __launch_bounds__(256) void ff2_combine_kernel(
    const bf16* __restrict__ p0, const bf16* __restrict__ p1,
    const float* __restrict__ b2, const float* __restrict__ x1,
    float* __restrict__ out) {
    const int i = (blockIdx.x * 256 + threadIdx.x) * 4;
    bf16x4 a = *(const bf16x4*)(p0 + i);
    bf16x4 b = *(const bf16x4*)(p1 + i);
    F4 xr; xr.v = *(const float4*)(x1 + i);
    const int col = i % DMODEL;
    F4 o;
#pragma unroll
    for (int j = 0; j < 4; ++j)
        o.f[j] = (float)a[j] + (float)b[j] + b2[col + j] + xr.f[j];
    *(float4*)(out + i) = o.v;
}

// ---------------- Transposed-S MFMA flash attention (R6 config + shfl-free PV) ----------------
// S^T = K·Q^T. PV uses 16x16x16 MFMA whose B-layout matches S^T's C-layout
// exactly -> P feeds PV with no shfl / LDS round trip. Q pre-scaled.
// grid (32,H,B) = 768 paired-uniform blocks ({63-bx, bx} -> 65 iters).
// Double-buffered K/V, 1 barrier/iter.
__global__ __launch_bounds__(256) void mattn_kernel(
    const bf16* __restrict__ Q, const bf16* __restrict__ K,
    const bf16* __restrict__ V, const int* __restrict__ amask,
    bf16* __restrict__ O) {
    const int bx = blockIdx.x, h = blockIdx.y, b = blockIdx.z;

    __shared__ bf16 Ks[2][64][68];   // [buf][key][d]  (136 B rows: conflict-free)
    __shared__ bf16 Vt[2][64][68];   // [buf][d][key]
    __shared__ bf16 Os[64][68];      // epilogue bounce
    __shared__ float mk[2][64];
    __shared__ int flagv[2];

    const int tid = threadIdx.x;
    const int wave = tid >> 6, lane = tid & 63;
    const int l = lane & 15, quad = lane >> 4;
#if !HAVE_MFMA16
    const int qh = quad >> 1;
    const int srcA = (quad & 1) * 32 + l;
    const int srcB = srcA + 16;
#endif
    const float NEG_INF = -__builtin_huge_valf();

    const int kr = tid >> 2, ks = (tid & 3) * 16;          // K tile staging
    const int vk0 = (tid & 31) * 2, vds = (tid >> 5) * 8;  // V transpose staging

    const bf16* Kbase = K + (size_t)b * S_LEN * DMODEL + h * HDIM;
    const bf16* Vbase = V + (size_t)b * S_LEN * DMODEL + h * HDIM;

#pragma unroll 1
    for (int pass = 0; pass < 2; ++pass) {
        const int qt = pass ? bx : (63 - bx);

        const bf16* Qb = Q + (size_t)(b * S_LEN + qt * 64 + wave * 16 + l) * DMODEL + h * HDIM;
        const bf16x8 qf0 = *(const bf16x8*)(Qb + quad * 8);
        const bf16x8 qf1 = *(const bf16x8*)(Qb + 32 + quad * 8);

        float m_run = NEG_INF, l_run = 0.0f;
        f32x4 acc[4] = {};

        // ---- prefetch tile 0 into registers ----
        bf16x8 kp0, kp1, vp0, vp1;
        int mv = 1;
        {
            const bf16* kg = Kbase + (size_t)kr * DMODEL + ks;
            kp0 = *(const bf16x8*)kg;
            kp1 = *(const bf16x8*)(kg + 8);
            const bf16* vg = Vbase + (size_t)vk0 * DMODEL + vds;
            vp0 = *(const bf16x8*)vg;
            vp1 = *(const bf16x8*)(vg + DMODEL);
            if (wave == 0) mv = amask[b * S_LEN + lane];
        }
        __syncthreads();   // prior pass epilogue LDS reads complete
        {
            *(bf16x8*)&Ks[0][kr][ks]     = kp0;
            *(bf16x8*)&Ks[0][kr][ks + 8] = kp1;
#pragma unroll
            for (int i = 0; i < 8; ++i) {
                U2 w; w.h[0] = vp0[i]; w.h[1] = vp1[i];
                *(unsigned*)&Vt[0][vds + i][vk0] = w.u;
            }
            if (wave == 0) {
                mk[0][lane] = mv ? 0.0f : NEG_INF;
                unsigned long long bal = __ballot(mv != 0);
                if (lane == 0) flagv[0] = (bal == ~0ULL);
            }
        }
        __syncthreads();
        int buf = 0;

        for (int kt = 0; kt <= qt; ++kt) {
            const bool more = (kt < qt);
            if (more) {
                const bf16* kg = Kbase + (size_t)((kt + 1) * 64 + kr) * DMODEL + ks;
                kp0 = *(const bf16x8*)kg;
                kp1 = *(const bf16x8*)(kg + 8);
                const bf16* vg = Vbase + (size_t)((kt + 1) * 64 + vk0) * DMODEL + vds;
                vp0 = *(const bf16x8*)vg;
                vp1 = *(const bf16x8*)(vg + DMODEL);
                if (wave == 0) mv = amask[b * S_LEN + (kt + 1) * 64 + lane];
            }

            const int allv = flagv[buf];
            f32x4 sreg[4] = {};
#pragma unroll
            for (int mi = 0; mi < 4; ++mi) {
                bf16x8 kf0 = *(const bf16x8*)&Ks[buf][mi * 16 + l][quad * 8];
                bf16x8 kf1 = *(const bf16x8*)&Ks[buf][mi * 16 + l][32 + quad * 8];
                sreg[mi] = __builtin_amdgcn_mfma_f32_16x16x32_bf16(kf0, qf0, sreg[mi], 0, 0, 0);
                sreg[mi] = __builtin_amdgcn_mfma_f32_16x16x32_bf16(kf1, qf1, sreg[mi], 0, 0, 0);
            }
            if (!allv) {
#pragma unroll
                for (int mi = 0; mi < 4; ++mi) {
                    F4 m4; m4.v = *(const float4*)&mk[buf][mi * 16 + quad * 4];
#pragma unroll
                    for (int r = 0; r < 4; ++r) sreg[mi][r] += m4.f[r];
                }
            }
            if (kt == qt) {
#pragma unroll
                for (int mi = 0; mi < 4; ++mi)
#pragma unroll
                    for (int r = 0; r < 4; ++r)
                        if (mi * 16 + quad * 4 + r > wave * 16 + l)
                            sreg[mi][r] = NEG_INF;
            }

            // online softmax (per-lane: one query's 16 keys; 2 shfl levels)
            float mloc = sreg[0][0];
#pragma unroll
            for (int mi = 0; mi < 4; ++mi)
#pragma unroll
                for (int r = 0; r < 4; ++r) mloc = fmaxf(mloc, sreg[mi][r]);
            mloc = fmaxf(mloc, __shfl_xor(mloc, 16, 64));
            mloc = fmaxf(mloc, __shfl_xor(mloc, 32, 64));
            const float mn = fmaxf(m_run, mloc);
            const float alpha = __builtin_amdgcn_exp2f(m_run - mn);
            m_run = mn;
            float ls = 0.0f;
#pragma unroll
            for (int mi = 0; mi < 4; ++mi)
#pragma unroll
                for (int r = 0; r < 4; ++r) {
                    const float p = __builtin_amdgcn_exp2f(sreg[mi][r] - mn);
                    sreg[mi][r] = p;
                    ls += p;
                }
            ls += __shfl_xor(ls, 16, 64);
            ls += __shfl_xor(ls, 32, 64);
            l_run = l_run * alpha + ls;
#pragma unroll
            for (int mi = 0; mi < 4; ++mi)
#pragma unroll
                for (int r = 0; r < 4; ++r) acc[mi][r] *= alpha;

            // pack P^T to bf16 dwords (keys mi*16+quad*4+{0..3}, query l)
            unsigned pk[4][2];
#pragma unroll
            for (int mi = 0; mi < 4; ++mi) {
                U2 w0; w0.h[0] = (bf16)sreg[mi][0]; w0.h[1] = (bf16)sreg[mi][1];
                U2 w1; w1.h[0] = (bf16)sreg[mi][2]; w1.h[1] = (bf16)sreg[mi][3];
                pk[mi][0] = w0.u; pk[mi][1] = w1.u;
            }

#if HAVE_MFMA16
            // O^T += V^T · P^T via 16x16x16: B-frag = pk[mi] directly (no shfl).
#pragma unroll
            for (int mi = 0; mi < 4; ++mi) {
                U4 pb; pb.u[0] = pk[mi][0]; pb.u[1] = pk[mi][1];
#pragma unroll
                for (int di = 0; di < 4; ++di) {
                    mf16_t va = *(const mf16_t*)&Vt[buf][di * 16 + l][mi * 16 + quad * 4];
                    acc[di] = MFMA16(va, pb.v, acc[di]);
                }
            }
#else
            // fallback: assemble 16x16x32 B-frags via quad-level shfl
            bf16x8 pfrag[2];
#pragma unroll
            for (int kc = 0; kc < 2; ++kc) {
                U8 u;
#pragma unroll
                for (int t = 0; t < 2; ++t) {
                    const unsigned a0 = (unsigned)__shfl((int)pk[2 * kc][t],     srcA, 64);
                    const unsigned b0 = (unsigned)__shfl((int)pk[2 * kc + 1][t], srcA, 64);
                    u.u[t] = qh ? b0 : a0;
                    const unsigned a1 = (unsigned)__shfl((int)pk[2 * kc][t],     srcB, 64);
                    const unsigned b1 = (unsigned)__shfl((int)pk[2 * kc + 1][t], srcB, 64);
                    u.u[2 + t] = qh ? b1 : a1;
                }
                pfrag[kc] = u.v;
            }
#pragma unroll
            for (int mi = 0; mi < 4; ++mi) {
                bf16x8 vf0 = *(const bf16x8*)&Vt[buf][mi * 16 + l][quad * 8];
                bf16x8 vf1 = *(const bf16x8*)&Vt[buf][mi * 16 + l][32 + quad * 8];
                acc[mi] = __builtin_amdgcn_mfma_f32_16x16x32_bf16(vf0, pfrag[0], acc[mi], 0, 0, 0);
                acc[mi] = __builtin_amdgcn_mfma_f32_16x16x32_bf16(vf1, pfrag[1], acc[mi], 0, 0, 0);
            }
#endif

            if (more) {
                const int nb = buf ^ 1;
                *(bf16x8*)&Ks[nb][kr][ks]     = kp0;
                *(bf16x8*)&Ks[nb][kr][ks + 8] = kp1;
#pragma unroll
                for (int i = 0; i < 8; ++i) {
                    U2 w; w.h[0] = vp0[i]; w.h[1] = vp1[i];
                    *(unsigned*)&Vt[nb][vds + i][vk0] = w.u;
                }
                if (wave == 0) {
                    mk[nb][lane] = mv ? 0.0f : NEG_INF;
                    unsigned long long bal = __ballot(mv != 0);
                    if (lane == 0) flagv[nb] = (bal == ~0ULL);
                }
            }
            __syncthreads();
            buf ^= 1;
        }

        const float rinv = 1.0f / l_run;
#pragma unroll
        for (int mi = 0; mi < 4; ++mi) {
            U2 w0; w0.h[0] = (bf16)(acc[mi][0] * rinv); w0.h[1] = (bf16)(acc[mi][1] * rinv);
            U2 w1; w1.h[0] = (bf16)(acc[mi][2] * rinv); w1.h[1] = (bf16)(acc[mi][3] * rinv);
            *(unsigned*)&Os[wave * 16 + l][mi * 16 + quad * 4]     = w0.u;
            *(unsigned*)&Os[wave * 16 + l][mi * 16 + quad * 4 + 2] = w1.u;
        }
        __syncthreads();
        {
            const int orow = tid >> 2, oseg = (tid & 3) * 16;
            bf16* Og = O + (size_t)(b * S_LEN + qt * 64 + orow) * DMODEL + h * HDIM + oseg;
            *(bf16x8*)Og       = *(const bf16x8*)&Os[orow][oseg];
            *(bf16x8*)(Og + 8) = *(const bf16x8*)&Os[orow][oseg + 8];
        }
    }
}

// ---------------- launcher ----------------
extern "C" void kernel_launch(void* const* d_in, const int* in_sizes, int n_in,
                              void* d_out, int out_size, void* d_ws, size_t ws_size,
                              hipStream_t stream) {
    const float* x     = (const float*)d_in[0];
    const int*   amask = (const int*)  d_in[1];
    const float* ln1_g = (const float*)d_in[2];
    const float* ln1_b = (const float*)d_in[3];
    const float* ln2_g = (const float*)d_in[4];
    const float* ln2_b = (const float*)d_in[5];
    const float* Wq = (const float*)d_in[6];  const float* bq = (const float*)d_in[7];
    const float* Wk = (const float*)d_in[8];  const float* bk = (const float*)d_in[9];
    const float* Wv = (const float*)d_in[10]; const float* bv = (const float*)d_in[11];
    const float* Wo = (const float*)d_in[12]; const float* bo = (const float*)d_in[13];
    const float* W1 = (const float*)d_in[14]; const float* b1 = (const float*)d_in[15];
    const float* W2 = (const float*)d_in[16]; const float* b2 = (const float*)d_in[17];
    float* out = (float*)d_out;

    char* ws = (char*)d_ws;
    const size_t WSML = (size_t)DMODEL * DMODEL * 2;
    const size_t WBIG = (size_t)DMODEL * DFF_ * 2;
    bf16* Wqt = (bf16*)(ws + 0 * WSML);
    bf16* Wkt = (bf16*)(ws + 1 * WSML);
    bf16* Wvt = (bf16*)(ws + 2 * WSML);
    bf16* Wot = (bf16*)(ws + 3 * WSML);
    bf16* W1t = (bf16*)(ws + 4 * WSML);
    bf16* W2t = (bf16*)(ws + 4 * WSML + WBIG);
    char* act = ws + 4 * WSML + 2 * WBIG;

    const size_t HB = (size_t)MROWS * DMODEL * 2;   // bf16 activation (12.6 MB)
    const size_t FB = (size_t)MROWS * DMODEL * 4;   // fp32 activation (25.2 MB)
    bf16*  h    = (bf16*)(act);            // LN1 out; later ctx; later h2
    bf16*  qb   = (bf16*)(act + HB);
    bf16*  kb   = (bf16*)(act + 2 * HB);
    bf16*  vb   = (bf16*)(act + 3 * HB);
    bf16*  ctx  = h;
    float* x1   = (float*)(act + 4 * HB);
    bf16*  f    = (bf16*)(act + 4 * HB + FB);      // FF1 out: 8192x3072 bf16 (50.3 MB)
    bf16*  h2   = h;
    bf16*  p0   = qb;                               // FF2 split-K partials (dead q/k bufs)
    bf16*  p1   = kb;
    float* zbias = (float*)vb;                      // zero bias (dead vb)

    const float SCL = 0.125f * 1.44269504089f;  // 1/sqrt(64) * log2(e), folded into Q

    // 0. fused weight transpose+convert (one launch, 1728 tiles)
    wtrans_all_kernel<<<1728, 256, 0, stream>>>(Wq, Wk, Wv, Wo, W1, W2,
                                                Wqt, Wkt, Wvt, Wot, W1t, W2t);

    // 1. LN1 -> h (bf16)
    ln_kernel<bf16><<<MROWS, 256, 0, stream>>>(x, ln1_g, ln1_b, h);
    // 2. QKV fused, bf16 out; Q pre-scaled by SCL  (1152 blocks, 12 BK64-iters)
    mgemm_kernel<128, false, false, true><<<dim3(DMODEL / 128, MROWS / 128, 3), 256, 0, stream>>>(
        h, Wqt, bq, qb, Wkt, bk, kb, Wvt, bv, vb, nullptr,
        MROWS, DMODEL, DMODEL, DMODEL, 0, 0, 0, SCL, 1.0f, 1.0f);
    // 3. flash attention -> ctx (bf16)  (768 paired-uniform blocks)
    mattn_kernel<<<dim3(32, NHEAD, 2), 256, 0, stream>>>(qb, kb, vb, amask, ctx);
    // zero bias buffer for split-K partials (vb dead now)
    hipMemsetAsync(zbias, 0, DMODEL * sizeof(float), stream);
    // 4. out proj + residual(x) -> x1 (fp32)  (MT=64: 768 blocks, 12 iters)
    mgemm_kernel<64, false, true, false><<<dim3(DMODEL / 128, MROWS / 64, 1), 256, 0, stream>>>(
        ctx, Wot, bo, x1, Wot, bo, x1, Wot, bo, x1, x,
        MROWS, DMODEL, DMODEL, DMODEL, 0, 0, 0, 1.0f, 1.0f, 1.0f);
    // 5. LN2 -> h2 (bf16)
    ln_kernel<bf16><<<MROWS, 256, 0, stream>>>(x1, ln2_g, ln2_b, h2);
    // 6. FF1 + relu -> f (bf16)  (1536 blocks, 12 iters)
    mgemm_kernel<128, true, false, true><<<dim3(DFF_ / 128, MROWS / 128, 1), 256, 0, stream>>>(
        h2, W1t, b1, f, W1t, b1, f, W1t, b1, f, nullptr,
        MROWS, DFF_, DMODEL, DMODEL, 0, 0, 0, 1.0f, 1.0f, 1.0f);
    // 7. FF2 split-K: z=0 -> K[0,1536) into p0; z=1 -> K[1536,3072) into p1
    //    (768 blocks, 24 BK64-iters each)
    mgemm_kernel<128, false, false, true><<<dim3(DMODEL / 128, MROWS / 128, 2), 256, 0, stream>>>(
        f, W2t, zbias, p0, W2t, zbias, p1, W2t, zbias, p1, nullptr,
        MROWS, DMODEL, DFF_, DFF_ / 2, 0, DFF_ / 2, 0, 1.0f, 1.0f, 1.0f);
    // 7b. combine: out = p0 + p1 + b2 + x1  (6144 blocks)
    ff2_combine_kernel<<<(MROWS * DMODEL) / 1024, 256, 0, stream>>>(p0, p1, b2, x1, out);
}

// Round 13
// 458.052 us; speedup vs baseline: 1.5519x; 1.0259x over previous
//
#include <hip/hip_runtime.h>
#include <hip/hip_bf16.h>
#include <math.h>

#define S_LEN 4096
#define DMODEL 768
#define NHEAD 12
#define HDIM 64
#define DFF_ 3072
#define MROWS 8192  // B*S

typedef __bf16 bf16;
typedef __bf16 bf16x4 __attribute__((ext_vector_type(4)));
typedef __bf16 bf16x8 __attribute__((ext_vector_type(8)));
typedef float f32x4 __attribute__((ext_vector_type(4)));
typedef short s16x4 __attribute__((ext_vector_type(4)));

union F4 { float4 v; float f[4]; };
union U2 { bf16 h[2]; unsigned u; };
union U8 { unsigned u[4]; bf16x8 v; };

// 16x16x16 bf16 MFMA: B-operand layout B[k=quad*4+j][n=l] == S^T C-layout,
// so softmax'd P feeds PV directly with ZERO cross-lane movement.
#if __has_builtin(__builtin_amdgcn_mfma_f32_16x16x16bf16_1k)
typedef s16x4 mf16_t;
#define MFMA16(a, b, c) __builtin_amdgcn_mfma_f32_16x16x16bf16_1k((a), (b), (c), 0, 0, 0)
#define HAVE_MFMA16 1
#elif __has_builtin(__builtin_amdgcn_mfma_f32_16x16x16_bf16)
typedef bf16x4 mf16_t;
#define MFMA16(a, b, c) __builtin_amdgcn_mfma_f32_16x16x16_bf16((a), (b), (c), 0, 0, 0)
#define HAVE_MFMA16 1
#else
#define HAVE_MFMA16 0
#endif

#if HAVE_MFMA16
union U4 { unsigned u[2]; mf16_t v; };
#endif

__device__ __forceinline__ void gld_lds16(void* lds, const void* g) {
    __builtin_amdgcn_global_load_lds(
        (const __attribute__((address_space(1))) unsigned int*)g,
        (__attribute__((address_space(3))) unsigned int*)lds, 16, 0, 0);
}

// ---------------- LayerNorm (optionally zero-fills the 768-float zbias buf) ----------------
template<typename OUT>
__global__ __launch_bounds__(256) void ln_kernel(const float* __restrict__ x,
                                                 const float* __restrict__ g,
                                                 const float* __restrict__ bta,
                                                 OUT* __restrict__ out,
                                                 float* __restrict__ zb) {
    const int row = blockIdx.x;
    const int t = threadIdx.x;
    // zbias zero-fill: runs at LN2 time (after vb is dead, before FF2 reads it)
    if (zb && row == 0 && t < 192)
        ((float4*)zb)[t] = make_float4(0.f, 0.f, 0.f, 0.f);
    const float* xr = x + (size_t)row * DMODEL;
    float v0 = xr[t], v1 = xr[t + 256], v2 = xr[t + 512];
    float s = v0 + v1 + v2;
    float ss = v0 * v0 + v1 * v1 + v2 * v2;
    for (int o = 32; o > 0; o >>= 1) {
        s += __shfl_down(s, o, 64);
        ss += __shfl_down(ss, o, 64);
    }
    __shared__ float sm[4], sm2[4];
    const int w = t >> 6, lane = t & 63;
    if (lane == 0) { sm[w] = s; sm2[w] = ss; }
    __syncthreads();
    s = sm[0] + sm[1] + sm[2] + sm[3];
    ss = sm2[0] + sm2[1] + sm2[2] + sm2[3];
    const float mu = s * (1.0f / DMODEL);
    const float var = ss * (1.0f / DMODEL) - mu * mu;
    const float rs = rsqrtf(var + 1e-5f);
    OUT* orow = out + (size_t)row * DMODEL;
    orow[t]       = (OUT)((v0 - mu) * rs * g[t]       + bta[t]);
    orow[t + 256] = (OUT)((v1 - mu) * rs * g[t + 256] + bta[t + 256]);
    orow[t + 512] = (OUT)((v2 - mu) * rs * g[t + 512] + bta[t + 512]);
}

// ---------------- fused weight transpose+convert: all 6 weights, one launch ----------------
__global__ __launch_bounds__(256) void wtrans_all_kernel(
    const float* __restrict__ Wq, const float* __restrict__ Wk,
    const float* __restrict__ Wv, const float* __restrict__ Wo,
    const float* __restrict__ W1, const float* __restrict__ W2,
    bf16* __restrict__ Wqt, bf16* __restrict__ Wkt, bf16* __restrict__ Wvt,
    bf16* __restrict__ Wot, bf16* __restrict__ W1t, bf16* __restrict__ W2t) {
    int t = blockIdx.x;
    const float* W; bf16* Wt; int K, N;
    if      (t < 144)  { W = Wq; Wt = Wqt; K = 768;  N = 768;  }
    else if (t < 288)  { W = Wk; Wt = Wkt; K = 768;  N = 768;  t -= 144; }
    else if (t < 432)  { W = Wv; Wt = Wvt; K = 768;  N = 768;  t -= 288; }
    else if (t < 576)  { W = Wo; Wt = Wot; K = 768;  N = 768;  t -= 432; }
    else if (t < 1152) { W = W1; Wt = W1t; K = 768;  N = 3072; t -= 576; }
    else               { W = W2; Wt = W2t; K = 3072; N = 768;  t -= 1152; }
    const int nx = N >> 6;
    const int n0 = (t % nx) * 64, k0 = (t / nx) * 64;

    __shared__ float tile[64][65];
    const int tid = threadIdx.x;
    const int lr = tid >> 4, lc = (tid & 15) << 2;
#pragma unroll
    for (int i = 0; i < 4; ++i) {
        const int r = lr + i * 16;
        F4 w; w.v = *(const float4*)&W[(size_t)(k0 + r) * N + n0 + lc];
#pragma unroll
        for (int j = 0; j < 4; ++j) tile[r][lc + j] = w.f[j];
    }
    __syncthreads();
#pragma unroll
    for (int i = 0; i < 4; ++i) {
        const int n = lr + i * 16;
        bf16x4 o;
#pragma unroll
        for (int j = 0; j < 4; ++j) o[j] = (bf16)tile[lc + j][n];
        *(bf16x4*)&Wt[(size_t)(n0 + n) * K + k0 + lc] = o;
    }
}

// ---------------- bf16 MFMA GEMM, MT x 128 tile, BK=64 ----------------
template<int MT, bool RELU, bool RES, bool OUT_BF16>
__global__ __launch_bounds__(256) void mgemm_kernel(
    const bf16* __restrict__ A,
    const bf16* __restrict__ Wt0, const float* __restrict__ bias0, void* __restrict__ C0,
    const bf16* __restrict__ Wt1, const float* __restrict__ bias1, void* __restrict__ C1,
    const bf16* __restrict__ Wt2, const float* __restrict__ bias2, void* __restrict__ C2,
    const float* __restrict__ R, int M, int N, int K, int Kloop,
    int koff0, int koff1, int koff2,
    float sc0, float sc1, float sc2) {
    const bf16* Wt = Wt0; const float* bias = bias0; void* C = C0; float sc = sc0; int koff = koff0;
    if (blockIdx.z == 1) { Wt = Wt1; bias = bias1; C = C1; sc = sc1; koff = koff1; }
    if (blockIdx.z == 2) { Wt = Wt2; bias = bias2; C = C2; sc = sc2; koff = koff2; }

    constexpr int NI = (MT == 128) ? 4 : 2;
    __shared__ bf16 As[2][MT * 32];
    __shared__ bf16 Bs[2][128 * 32];

    const int tid = threadIdx.x;
    const int wave = tid >> 6, lane = tid & 63;
    const int row0 = blockIdx.y * MT, col0 = blockIdx.x * 128;
    const int wr = (MT == 128) ? (wave >> 1) * 64 : 0;
    const int wc = (MT == 128) ? (wave & 1) * 64 : wave * 32;
    const int mrow = lane & 15, kq = (lane >> 4) * 8;

    const int st_row = (lane >> 2);
    const int st_off = (lane & 3) * 16;

    f32x4 acc[4][NI] = {};

    const char* Ab = (const char*)(A + (size_t)row0 * K + koff);
    const char* Bb = (const char*)(Wt + (size_t)col0 * K + koff);
    const size_t strideA = (size_t)K * 2;

    for (int k0 = 0; k0 < Kloop; k0 += 64) {
#pragma unroll
        for (int s = 0; s < 2; ++s) {
            const int kk = k0 + s * 32;
            if (MT == 128) {
#pragma unroll
                for (int issue = 0; issue < 2; ++issue) {
                    const int r = wave * 32 + issue * 16 + st_row;
                    gld_lds16((char*)As[s] + (wave * 32 + issue * 16) * 64,
                              Ab + (size_t)r * strideA + kk * 2 + st_off);
                }
            } else {
                const int r = wave * 16 + st_row;
                gld_lds16((char*)As[s] + (wave * 16) * 64,
                          Ab + (size_t)r * strideA + kk * 2 + st_off);
            }
#pragma unroll
            for (int issue = 0; issue < 2; ++issue) {
                const int r = wave * 32 + issue * 16 + st_row;
                gld_lds16((char*)Bs[s] + (wave * 32 + issue * 16) * 64,
                          Bb + (size_t)r * strideA + kk * 2 + st_off);
            }
        }
        __syncthreads();
#pragma unroll
        for (int s = 0; s < 2; ++s) {
            bf16x8 af[4], bfr[NI];
#pragma unroll
            for (int mi = 0; mi < 4; ++mi)
                af[mi] = *(const bf16x8*)&As[s][(wr + mi * 16 + mrow) * 32 + kq];
#pragma unroll
            for (int ni = 0; ni < NI; ++ni)
                bfr[ni] = *(const bf16x8*)&Bs[s][(wc + ni * 16 + mrow) * 32 + kq];
#pragma unroll
            for (int mi = 0; mi < 4; ++mi)
#pragma unroll
                for (int ni = 0; ni < NI; ++ni)
                    acc[mi][ni] = __builtin_amdgcn_mfma_f32_16x16x32_bf16(
                        af[mi], bfr[ni], acc[mi][ni], 0, 0, 0);
        }
        __syncthreads();
    }

    const int quad = lane >> 4;
    float bv[NI];
#pragma unroll
    for (int ni = 0; ni < NI; ++ni) bv[ni] = bias[col0 + wc + ni * 16 + mrow];
#pragma unroll
    for (int mi = 0; mi < 4; ++mi) {
#pragma unroll
        for (int r = 0; r < 4; ++r) {
            const int row = row0 + wr + mi * 16 + quad * 4 + r;
#pragma unroll
            for (int ni = 0; ni < NI; ++ni) {
                const int col = col0 + wc + ni * 16 + mrow;
                float v = acc[mi][ni][r] + bv[ni];
                if (RES) v += R[(size_t)row * N + col];
                v *= sc;
                if (RELU) v = fmaxf(v, 0.0f);
                if (OUT_BF16) ((bf16*)C)[(size_t)row * N + col] = (bf16)v;
                else          ((float*)C)[(size_t)row * N + col] = v;
            }
        }
    }
}

// ---------------- FF2 split-K combine: out = p0 + p1 + b2 + x1 ----------------
__global__ __launch_bounds__(256) void ff2_combine_kernel(
    const bf16* __restrict__ p0, const bf16* __restrict__ p1,
    const float* __restrict__ b2, const float* __restrict__ x1,
    float* __restrict__ out) {
    const int i = (blockIdx.x * 256 + threadIdx.x) * 4;
    bf16x4 a = *(const bf16x4*)(p0 + i);
    bf16x4 b = *(const bf16x4*)(p1 + i);
    F4 xr; xr.v = *(const float4*)(x1 + i);
    const int col = i % DMODEL;
    F4 o;
#pragma unroll
    for (int j = 0; j < 4; ++j)
        o.f[j] = (float)a[j] + (float)b[j] + b2[col + j] + xr.f[j];
    *(float4*)(out + i) = o.v;
}

// ---------------- Transposed-S MFMA flash attention (shfl-free PV + MFMA-fused l) ----------------
// S^T = K·Q^T. PV uses 16x16x16 MFMA (B-layout == S^T C-layout: no shfl).
// Row-sum l fused into PV via a ones-row appended to V^T (row 64): only D-row 0
// reads the ones row, so garbage in rows 65..79 never contaminates acc_l[0];
// alpha rescale keeps acc_l consistent (first-iter alpha=0 clears init state).
// grid (32,H,B) = 768 paired-uniform blocks; double-buffered K/V, 1 barrier/iter.
__global__ __launch_bounds__(256) void mattn_kernel(
    const bf16* __restrict__ Q, const bf16* __restrict__ K,
    const bf16* __restrict__ V, const int* __restrict__ amask,
    bf16* __restrict__ O) {
    const int bx = blockIdx.x, h = blockIdx.y, b = blockIdx.z;

    __shared__ bf16 Ks[2][64][68];   // [buf][key][d]  (136 B rows: conflict-free)
#if HAVE_MFMA16
    __shared__ bf16 Vt[2][80][68];   // [buf][d][key]; row 64 = ones (l fusion)
#else
    __shared__ bf16 Vt[2][64][68];
#endif
    __shared__ bf16 Os[64][68];      // epilogue bounce
    __shared__ float mk[2][64];
    __shared__ int flagv[2];

    const int tid = threadIdx.x;
    const int wave = tid >> 6, lane = tid & 63;
    const int l = lane & 15, quad = lane >> 4;
#if !HAVE_MFMA16
    const int qh = quad >> 1;
    const int srcA = (quad & 1) * 32 + l;
    const int srcB = srcA + 16;
#endif
    const float NEG_INF = -__builtin_huge_valf();

    const int kr = tid >> 2, ks = (tid & 3) * 16;          // K tile staging
    const int vk0 = (tid & 31) * 2, vds = (tid >> 5) * 8;  // V transpose staging

    const bf16* Kbase = K + (size_t)b * S_LEN * DMODEL + h * HDIM;
    const bf16* Vbase = V + (size_t)b * S_LEN * DMODEL + h * HDIM;

#if HAVE_MFMA16
    // ones row for l-fusion (row 64 of both V^T buffers); staging never touches
    // rows >= 64, so this survives the whole kernel. Visible after first barrier.
    if (tid < 68) {
        Vt[0][64][tid] = (bf16)1.0f;
        Vt[1][64][tid] = (bf16)1.0f;
    }
#endif

#pragma unroll 1
    for (int pass = 0; pass < 2; ++pass) {
        const int qt = pass ? bx : (63 - bx);

        const bf16* Qb = Q + (size_t)(b * S_LEN + qt * 64 + wave * 16 + l) * DMODEL + h * HDIM;
        const bf16x8 qf0 = *(const bf16x8*)(Qb + quad * 8);
        const bf16x8 qf1 = *(const bf16x8*)(Qb + 32 + quad * 8);

        float m_run = NEG_INF;
#if !HAVE_MFMA16
        float l_run = 0.0f;
#endif
        f32x4 acc[4] = {};
#if HAVE_MFMA16
        f32x4 acc_l = {};   // D-row 0 (quad-0 lanes, elem 0) accumulates l
#endif

        // ---- prefetch tile 0 into registers ----
        bf16x8 kp0, kp1, vp0, vp1;
        int mv = 1;
        {
            const bf16* kg = Kbase + (size_t)kr * DMODEL + ks;
            kp0 = *(const bf16x8*)kg;
            kp1 = *(const bf16x8*)(kg + 8);
            const bf16* vg = Vbase + (size_t)vk0 * DMODEL + vds;
            vp0 = *(const bf16x8*)vg;
            vp1 = *(const bf16x8*)(vg + DMODEL);
            if (wave == 0) mv = amask[b * S_LEN + lane];
        }
        __syncthreads();   // prior pass epilogue LDS reads complete
        {
            *(bf16x8*)&Ks[0][kr][ks]     = kp0;
            *(bf16x8*)&Ks[0][kr][ks + 8] = kp1;
#pragma unroll
            for (int i = 0; i < 8; ++i) {
                U2 w; w.h[0] = vp0[i]; w.h[1] = vp1[i];
                *(unsigned*)&Vt[0][vds + i][vk0] = w.u;
            }
            if (wave == 0) {
                mk[0][lane] = mv ? 0.0f : NEG_INF;
                unsigned long long bal = __ballot(mv != 0);
                if (lane == 0) flagv[0] = (bal == ~0ULL);
            }
        }
        __syncthreads();
        int buf = 0;

        for (int kt = 0; kt <= qt; ++kt) {
            const bool more = (kt < qt);
            if (more) {
                const bf16* kg = Kbase + (size_t)((kt + 1) * 64 + kr) * DMODEL + ks;
                kp0 = *(const bf16x8*)kg;
                kp1 = *(const bf16x8*)(kg + 8);
                const bf16* vg = Vbase + (size_t)((kt + 1) * 64 + vk0) * DMODEL + vds;
                vp0 = *(const bf16x8*)vg;
                vp1 = *(const bf16x8*)(vg + DMODEL);
                if (wave == 0) mv = amask[b * S_LEN + (kt + 1) * 64 + lane];
            }

            const int allv = flagv[buf];
            f32x4 sreg[4] = {};
#pragma unroll
            for (int mi = 0; mi < 4; ++mi) {
                bf16x8 kf0 = *(const bf16x8*)&Ks[buf][mi * 16 + l][quad * 8];
                bf16x8 kf1 = *(const bf16x8*)&Ks[buf][mi * 16 + l][32 + quad * 8];
                sreg[mi] = __builtin_amdgcn_mfma_f32_16x16x32_bf16(kf0, qf0, sreg[mi], 0, 0, 0);
                sreg[mi] = __builtin_amdgcn_mfma_f32_16x16x32_bf16(kf1, qf1, sreg[mi], 0, 0, 0);
            }
            if (!allv) {
#pragma unroll
                for (int mi = 0; mi < 4; ++mi) {
                    F4 m4; m4.v = *(const float4*)&mk[buf][mi * 16 + quad * 4];
#pragma unroll
                    for (int r = 0; r < 4; ++r) sreg[mi][r] += m4.f[r];
                }
            }
            if (kt == qt) {
#pragma unroll
                for (int mi = 0; mi < 4; ++mi)
#pragma unroll
                    for (int r = 0; r < 4; ++r)
                        if (mi * 16 + quad * 4 + r > wave * 16 + l)
                            sreg[mi][r] = NEG_INF;
            }

            // online softmax: max-reduce (15 max + 2 shfl), exp2, alpha rescale.
            float mloc = sreg[0][0];
#pragma unroll
            for (int mi = 0; mi < 4; ++mi)
#pragma unroll
                for (int r = 0; r < 4; ++r) mloc = fmaxf(mloc, sreg[mi][r]);
            mloc = fmaxf(mloc, __shfl_xor(mloc, 16, 64));
            mloc = fmaxf(mloc, __shfl_xor(mloc, 32, 64));
            const float mn = fmaxf(m_run, mloc);
            const float alpha = __builtin_amdgcn_exp2f(m_run - mn);
            m_run = mn;
#pragma unroll
            for (int mi = 0; mi < 4; ++mi)
#pragma unroll
                for (int r = 0; r < 4; ++r)
                    sreg[mi][r] = __builtin_amdgcn_exp2f(sreg[mi][r] - mn);
#if !HAVE_MFMA16
            float ls = 0.0f;
#pragma unroll
            for (int mi = 0; mi < 4; ++mi)
#pragma unroll
                for (int r = 0; r < 4; ++r) ls += sreg[mi][r];
            ls += __shfl_xor(ls, 16, 64);
            ls += __shfl_xor(ls, 32, 64);
            l_run = l_run * alpha + ls;
#endif
#pragma unroll
            for (int mi = 0; mi < 4; ++mi)
#pragma unroll
                for (int r = 0; r < 4; ++r) acc[mi][r] *= alpha;
#if HAVE_MFMA16
#pragma unroll
            for (int r = 0; r < 4; ++r) acc_l[r] *= alpha;
#endif

            // pack P^T to bf16 dwords (keys mi*16+quad*4+{0..3}, query l)
            unsigned pk[4][2];
#pragma unroll
            for (int mi = 0; mi < 4; ++mi) {
                U2 w0; w0.h[0] = (bf16)sreg[mi][0]; w0.h[1] = (bf16)sreg[mi][1];
                U2 w1; w1.h[0] = (bf16)sreg[mi][2]; w1.h[1] = (bf16)sreg[mi][3];
                pk[mi][0] = w0.u; pk[mi][1] = w1.u;
            }

#if HAVE_MFMA16
            // O^T += V^T · P^T ; extra MFMA on ones-row accumulates l into acc_l.
#pragma unroll
            for (int mi = 0; mi < 4; ++mi) {
                U4 pb; pb.u[0] = pk[mi][0]; pb.u[1] = pk[mi][1];
#pragma unroll
                for (int di = 0; di < 4; ++di) {
                    mf16_t va = *(const mf16_t*)&Vt[buf][di * 16 + l][mi * 16 + quad * 4];
                    acc[di] = MFMA16(va, pb.v, acc[di]);
                }
                mf16_t vl = *(const mf16_t*)&Vt[buf][64 + l][mi * 16 + quad * 4];
                acc_l = MFMA16(vl, pb.v, acc_l);
            }
#else
            bf16x8 pfrag[2];
#pragma unroll
            for (int kc = 0; kc < 2; ++kc) {
                U8 u;
#pragma unroll
                for (int t = 0; t < 2; ++t) {
                    const unsigned a0 = (unsigned)__shfl((int)pk[2 * kc][t],     srcA, 64);
                    const unsigned b0 = (unsigned)__shfl((int)pk[2 * kc + 1][t], srcA, 64);
                    u.u[t] = qh ? b0 : a0;
                    const unsigned a1 = (unsigned)__shfl((int)pk[2 * kc][t],     srcB, 64);
                    const unsigned b1 = (unsigned)__shfl((int)pk[2 * kc + 1][t], srcB, 64);
                    u.u[2 + t] = qh ? b1 : a1;
                }
                pfrag[kc] = u.v;
            }
#pragma unroll
            for (int mi = 0; mi < 4; ++mi) {
                bf16x8 vf0 = *(const bf16x8*)&Vt[buf][mi * 16 + l][quad * 8];
                bf16x8 vf1 = *(const bf16x8*)&Vt[buf][mi * 16 + l][32 + quad * 8];
                acc[mi] = __builtin_amdgcn_mfma_f32_16x16x32_bf16(vf0, pfrag[0], acc[mi], 0, 0, 0);
                acc[mi] = __builtin_amdgcn_mfma_f32_16x16x32_bf16(vf1, pfrag[1], acc[mi], 0, 0, 0);
            }
#endif

            if (more) {
                const int nb = buf ^ 1;
                *(bf16x8*)&Ks[nb][kr][ks]     = kp0;
                *(bf16x8*)&Ks[nb][kr][ks + 8] = kp1;
#pragma unroll
                for (int i = 0; i < 8; ++i) {
                    U2 w; w.h[0] = vp0[i]; w.h[1] = vp1[i];
                    *(unsigned*)&Vt[nb][vds + i][vk0] = w.u;
                }
                if (wave == 0) {
                    mk[nb][lane] = mv ? 0.0f : NEG_INF;
                    unsigned long long bal = __ballot(mv != 0);
                    if (lane == 0) flagv[nb] = (bal == ~0ULL);
                }
            }
            __syncthreads();
            buf ^= 1;
        }

#if HAVE_MFMA16
        // l lives in acc_l[0] of quad-0 lane with col==query; broadcast via shfl.
        const float l_run = __shfl(acc_l[0], l, 64);
#endif
        const float rinv = 1.0f / l_run;
#pragma unroll
        for (int mi = 0; mi < 4; ++mi) {
            U2 w0; w0.h[0] = (bf16)(acc[mi][0] * rinv); w0.h[1] = (bf16)(acc[mi][1] * rinv);
            U2 w1; w1.h[0] = (bf16)(acc[mi][2] * rinv); w1.h[1] = (bf16)(acc[mi][3] * rinv);
            *(unsigned*)&Os[wave * 16 + l][mi * 16 + quad * 4]     = w0.u;
            *(unsigned*)&Os[wave * 16 + l][mi * 16 + quad * 4 + 2] = w1.u;
        }
        __syncthreads();
        {
            const int orow = tid >> 2, oseg = (tid & 3) * 16;
            bf16* Og = O + (size_t)(b * S_LEN + qt * 64 + orow) * DMODEL + h * HDIM + oseg;
            *(bf16x8*)Og       = *(const bf16x8*)&Os[orow][oseg];
            *(bf16x8*)(Og + 8) = *(const bf16x8*)&Os[orow][oseg + 8];
        }
    }
}

// ---------------- launcher ----------------
extern "C" void kernel_launch(void* const* d_in, const int* in_sizes, int n_in,
                              void* d_out, int out_size, void* d_ws, size_t ws_size,
                              hipStream_t stream) {
    const float* x     = (const float*)d_in[0];
    const int*   amask = (const int*)  d_in[1];
    const float* ln1_g = (const float*)d_in[2];
    const float* ln1_b = (const float*)d_in[3];
    const float* ln2_g = (const float*)d_in[4];
    const float* ln2_b = (const float*)d_in[5];
    const float* Wq = (const float*)d_in[6];  const float* bq = (const float*)d_in[7];
    const float* Wk = (const float*)d_in[8];  const float* bk = (const float*)d_in[9];
    const float* Wv = (const float*)d_in[10]; const float* bv = (const float*)d_in[11];
    const float* Wo = (const float*)d_in[12]; const float* bo = (const float*)d_in[13];
    const float* W1 = (const float*)d_in[14]; const float* b1 = (const float*)d_in[15];
    const float* W2 = (const float*)d_in[16]; const float* b2 = (const float*)d_in[17];
    float* out = (float*)d_out;

    char* ws = (char*)d_ws;
    const size_t WSML = (size_t)DMODEL * DMODEL * 2;
    const size_t WBIG = (size_t)DMODEL * DFF_ * 2;
    bf16* Wqt = (bf16*)(ws + 0 * WSML);
    bf16* Wkt = (bf16*)(ws + 1 * WSML);
    bf16* Wvt = (bf16*)(ws + 2 * WSML);
    bf16* Wot = (bf16*)(ws + 3 * WSML);
    bf16* W1t = (bf16*)(ws + 4 * WSML);
    bf16* W2t = (bf16*)(ws + 4 * WSML + WBIG);
    char* act = ws + 4 * WSML + 2 * WBIG;

    const size_t HB = (size_t)MROWS * DMODEL * 2;   // bf16 activation (12.6 MB)
    const size_t FB = (size_t)MROWS * DMODEL * 4;   // fp32 activation (25.2 MB)
    bf16*  h    = (bf16*)(act);            // LN1 out; later ctx; later h2
    bf16*  qb   = (bf16*)(act + HB);
    bf16*  kb   = (bf16*)(act + 2 * HB);
    bf16*  vb   = (bf16*)(act + 3 * HB);
    bf16*  ctx  = h;
    float* x1   = (float*)(act + 4 * HB);
    bf16*  f    = (bf16*)(act + 4 * HB + FB);      // FF1 out (50.3 MB)
    bf16*  h2   = h;
    bf16*  p0   = qb;                               // FF2 split-K partials
    bf16*  p1   = kb;
    float* zbias = (float*)vb;                      // zero bias; re-zeroed at LN2
                                                    // (vb dead after attention)

    const float SCL = 0.125f * 1.44269504089f;  // 1/sqrt(64) * log2(e), folded into Q

    // 0. fused weight transpose+convert (one launch, 1728 tiles)
    wtrans_all_kernel<<<1728, 256, 0, stream>>>(Wq, Wk, Wv, Wo, W1, W2,
                                                Wqt, Wkt, Wvt, Wot, W1t, W2t);

    // 1. LN1 -> h (bf16)
    ln_kernel<bf16><<<MROWS, 256, 0, stream>>>(x, ln1_g, ln1_b, h, nullptr);
    // 2. QKV fused, bf16 out; Q pre-scaled by SCL  (1152 blocks)
    mgemm_kernel<128, false, false, true><<<dim3(DMODEL / 128, MROWS / 128, 3), 256, 0, stream>>>(
        h, Wqt, bq, qb, Wkt, bk, kb, Wvt, bv, vb, nullptr,
        MROWS, DMODEL, DMODEL, DMODEL, 0, 0, 0, SCL, 1.0f, 1.0f);
    // 3. flash attention -> ctx (bf16)  (768 paired-uniform blocks)
    mattn_kernel<<<dim3(32, NHEAD, 2), 256, 0, stream>>>(qb, kb, vb, amask, ctx);
    // 4. out proj + residual(x) -> x1 (fp32)  (MT=64: 768 blocks)
    mgemm_kernel<64, false, true, false><<<dim3(DMODEL / 128, MROWS / 64, 1), 256, 0, stream>>>(
        ctx, Wot, bo, x1, Wot, bo, x1, Wot, bo, x1, x,
        MROWS, DMODEL, DMODEL, DMODEL, 0, 0, 0, 1.0f, 1.0f, 1.0f);
    // 5. LN2 -> h2 (bf16) + zero zbias (vb dead now, before FF2 reads it)
    ln_kernel<bf16><<<MROWS, 256, 0, stream>>>(x1, ln2_g, ln2_b, h2, zbias);
    // 6. FF1 + relu -> f (bf16)  (1536 blocks)
    mgemm_kernel<128, true, false, true><<<dim3(DFF_ / 128, MROWS / 128, 1), 256, 0, stream>>>(
        h2, W1t, b1, f, W1t, b1, f, W1t, b1, f, nullptr,
        MROWS, DFF_, DMODEL, DMODEL, 0, 0, 0, 1.0f, 1.0f, 1.0f);
    // 7. FF2 split-K: z=0 -> K[0,1536) into p0; z=1 -> K[1536,3072) into p1
    mgemm_kernel<128, false, false, true><<<dim3(DMODEL / 128, MROWS / 128, 2), 256, 0, stream>>>(
        f, W2t, zbias, p0, W2t, zbias, p1, W2t, zbias, p1, nullptr,
        MROWS, DMODEL, DFF_, DFF_ / 2, 0, DFF_ / 2, 0, 1.0f, 1.0f, 1.0f);
    // 7b. combine: out = p0 + p1 + b2 + x1  (6144 blocks)
    ff2_combine_kernel<<<(MROWS * DMODEL) / 1024, 256, 0, stream>>>(p0, p1, b2, x1, out);
}